// Round 2
// baseline (825.524 us; speedup 1.0000x reference)
//
#include <hip/hip_runtime.h>

#define B 32
#define N 128
#define DD 32
#define H 64
#define C 10

typedef unsigned short bfu;   // raw bf16 storage

__device__ __forceinline__ float b2f(bfu v) {
    union { unsigned u; float f; } x; x.u = ((unsigned)v) << 16; return x.f;
}
__device__ __forceinline__ bfu f2b(float f) {
    union { float f; unsigned u; } x; x.f = f;
    unsigned r = x.u + 0x7fffu + ((x.u >> 16) & 1u);   // RNE
    return (bfu)(r >> 16);
}

// ---------------- small linear: out[row][c] = sum_k in[row*K+k]*W[k*H+c] (+bias)
template<int K, bool BIAS>
__global__ __launch_bounds__(64) void lin_kernel(const float* __restrict__ in,
                                                 const float* __restrict__ W,
                                                 const float* __restrict__ bias,
                                                 float* __restrict__ out) {
    int row = blockIdx.x;      // B*N rows
    int c = threadIdx.x;       // H = 64
    __shared__ float xs[K];
    if (threadIdx.x < K) xs[threadIdx.x] = in[(size_t)row * K + threadIdx.x];
    __syncthreads();
    float acc = BIAS ? bias[c] : 0.f;
#pragma unroll 8
    for (int k = 0; k < K; ++k) acc += xs[k] * W[k * H + c];
    out[(size_t)row * H + c] = acc;
}

// ---------------- h = relu(y1 + adj @ y2) per (b,i); full adj (with diagonal)
__global__ __launch_bounds__(64) void agg_relu_kernel(const float* __restrict__ y1,
                                                      const float* __restrict__ y2,
                                                      const float* __restrict__ adj,
                                                      float* __restrict__ hout) {
    int b = blockIdx.x / N, i = blockIdx.x % N;
    int d = threadIdx.x;
    __shared__ float arow[N];
    arow[d] = adj[((size_t)b * N + i) * N + d];
    arow[d + 64] = adj[((size_t)b * N + i) * N + 64 + d];
    __syncthreads();
    const float* y2b = y2 + (size_t)b * N * H;
    float acc = y1[((size_t)b * N + i) * H + d];
#pragma unroll 8
    for (int j = 0; j < N; ++j) acc += arow[j] * y2b[(size_t)j * H + d];
    hout[((size_t)b * N + i) * H + d] = fmaxf(acc, 0.f);
}

// ---------------- sum over middle axis: out[b][d] = sum_n in[b][n][d]
__global__ __launch_bounds__(64) void rowsum_kernel(const float* __restrict__ in,
                                                    float* __restrict__ out) {
    int b = blockIdx.x;
    int d = threadIdx.x;
    float acc = 0.f;
#pragma unroll 8
    for (int n = 0; n < N; ++n) acc += in[((size_t)b * N + n) * H + d];
    out[(size_t)b * H + d] = acc;
}

// ---------------- layer-1 aggregation: T[bl][j][i][d] = sum_w ac[b,i,w]*g[b,j,w,d]
// g[b,j,w,d] = U2[b,min(j,w),d] + V2[b,max(j,w),d] + ac[b,j,w]*w2last[d] + b2[d]
__global__ __launch_bounds__(256) void t1_kernel(const float* __restrict__ U2,
                                                 const float* __restrict__ V2,
                                                 const float* __restrict__ adj,
                                                 const float* __restrict__ w2last,
                                                 const float* __restrict__ b2,
                                                 bfu* __restrict__ T, int b0) {
    int bl = blockIdx.x / N, j = blockIdx.x % N;
    int b = b0 + bl;
    int t = threadIdx.x;
    __shared__ float Gj[N][H + 1];    // 33.3 KB
    __shared__ float At[32][N + 1];   // 16.5 KB
    {
        int d = t & 63; int w0 = t >> 6;
        const float* U2b = U2 + (size_t)b * N * H;
        const float* V2b = V2 + (size_t)b * N * H;
        const float* adjrow = adj + ((size_t)b * N + j) * N;
        float wl = w2last[d], bb = b2[d];
        for (int r = 0; r < 32; ++r) {
            int w = w0 + r * 4;
            int mn = min(j, w), mx = max(j, w);
            float a = (w == j) ? 0.f : adjrow[w];
            Gj[w][d] = U2b[(size_t)mn * H + d] + V2b[(size_t)mx * H + d] + a * wl + bb;
        }
    }
    float acc[8][4];
#pragma unroll
    for (int r = 0; r < 8; ++r)
#pragma unroll
        for (int q = 0; q < 4; ++q) acc[r][q] = 0.f;
    int ig = t >> 4, tg = t & 15;
    for (int wc = 0; wc < 4; ++wc) {
        __syncthreads();
        {
            int wi = t & 31; int i0 = t >> 5;
            for (int r = 0; r < 16; ++r) {
                int i = i0 + r * 8;
                int w = wc * 32 + wi;
                At[wi][i] = (i == w) ? 0.f : adj[((size_t)b * N + i) * N + w];
            }
        }
        __syncthreads();
#pragma unroll 8
        for (int wi = 0; wi < 32; ++wi) {
            int w = wc * 32 + wi;
            float g0 = Gj[w][tg * 4 + 0], g1 = Gj[w][tg * 4 + 1];
            float g2v = Gj[w][tg * 4 + 2], g3 = Gj[w][tg * 4 + 3];
#pragma unroll
            for (int r = 0; r < 8; ++r) {
                float a = At[wi][ig * 8 + r];
                acc[r][0] += a * g0; acc[r][1] += a * g1;
                acc[r][2] += a * g2v; acc[r][3] += a * g3;
            }
        }
    }
    bfu* Tj = T + ((size_t)(bl * N + j)) * N * H;
#pragma unroll
    for (int r = 0; r < 8; ++r) {
        ushort4 v;
        v.x = f2b(acc[r][0]); v.y = f2b(acc[r][1]);
        v.z = f2b(acc[r][2]); v.w = f2b(acc[r][3]);
        *(ushort4*)&Tj[(size_t)(ig * 8 + r) * H + tg * 4] = v;
    }
}

// ---------------- combine layer 1: pair[bl][i][j][d] = relu(self + T[bl,j,i,d] + T[bl,i,j,d])
__global__ __launch_bounds__(256) void combine1_kernel(const float* __restrict__ U1,
                                                       const float* __restrict__ V1,
                                                       const float* __restrict__ adj,
                                                       const float* __restrict__ w1last,
                                                       const float* __restrict__ b1,
                                                       const bfu* __restrict__ T,
                                                       bfu* __restrict__ pair, int b0) {
    int bl = blockIdx.x / N, i = blockIdx.x % N;
    int b = b0 + bl;
    int t = threadIdx.x;
    int d = t & 63; int jg = t >> 6;
    const float* U1b = U1 + (size_t)b * N * H;
    const float* V1b = V1 + (size_t)b * N * H;
    const float* adjrow = adj + ((size_t)b * N + i) * N;
    const bfu* Tb = T + (size_t)bl * N * N * H;
    bfu* pr = pair + ((size_t)(bl * N + i)) * N * H;
    float wl = w1last[d], bb = b1[d];
    for (int r = 0; r < 32; ++r) {
        int j = jg * 32 + r;
        int mn = min(i, j), mx = max(i, j);
        float a = (i == j) ? 0.f : adjrow[j];
        float self = U1b[(size_t)mn * H + d] + V1b[(size_t)mx * H + d] + a * wl + bb;
        float v = self + b2f(Tb[((size_t)j * N + i) * H + d]) + b2f(Tb[((size_t)i * N + j) * H + d]);
        pr[(size_t)j * H + d] = f2b(fmaxf(v, 0.f));
    }
}

// ---------------- layer-2 aggregation: g2[b,j,w,:] = pair[b,j,w,:]@W2 + b2; T2 = A@G
__global__ __launch_bounds__(256) void t2_kernel(const bfu* __restrict__ pair,
                                                 const float* __restrict__ W2,
                                                 const float* __restrict__ b2,
                                                 const float* __restrict__ adj,
                                                 bfu* __restrict__ T, int b0) {
    int bl = blockIdx.x / N, j = blockIdx.x % N;
    int b = b0 + bl;
    int t = threadIdx.x;
    __shared__ float Gj[N][H + 1];                 // 33.3 KB
    __shared__ union UU {
        struct { float W2s[H][H + 1]; float Pc[32][H + 1]; } a;  // 24.96 KB
        float At[32][N + 1];                                     // 16.5 KB
    } u;
    {
        int c = t & 63; int k0 = t >> 6;
        for (int r = 0; r < 16; ++r)
            u.a.W2s[k0 + r * 4][c] = W2[(size_t)(k0 + r * 4) * H + c];
    }
    const bfu* Pj = pair + ((size_t)(bl * N + j)) * N * H;
    float bb2 = b2[t & 63];
    for (int wc = 0; wc < 4; ++wc) {
        __syncthreads();
        {
            int k = t & 63; int w0 = t >> 6;
            for (int r = 0; r < 8; ++r) {
                int wl = w0 + r * 4;
                u.a.Pc[wl][k] = b2f(Pj[(size_t)(wc * 32 + wl) * H + k]);
            }
        }
        __syncthreads();
        {
            int d = t & 63; int w0 = t >> 6;
            for (int r = 0; r < 8; ++r) {
                int wl = w0 + r * 4;
                float acc = bb2;
#pragma unroll 16
                for (int k = 0; k < H; ++k) acc += u.a.Pc[wl][k] * u.a.W2s[k][d];
                Gj[wc * 32 + wl][d] = acc;
            }
        }
    }
    __syncthreads();
    float acc[8][4];
#pragma unroll
    for (int r = 0; r < 8; ++r)
#pragma unroll
        for (int q = 0; q < 4; ++q) acc[r][q] = 0.f;
    int ig = t >> 4, tg = t & 15;
    for (int wc = 0; wc < 4; ++wc) {
        {
            int wi = t & 31; int i0 = t >> 5;
            for (int r = 0; r < 16; ++r) {
                int i = i0 + r * 8;
                int w = wc * 32 + wi;
                u.At[wi][i] = (i == w) ? 0.f : adj[((size_t)b * N + i) * N + w];
            }
        }
        __syncthreads();
#pragma unroll 8
        for (int wi = 0; wi < 32; ++wi) {
            int w = wc * 32 + wi;
            float g0 = Gj[w][tg * 4 + 0], g1 = Gj[w][tg * 4 + 1];
            float g2v = Gj[w][tg * 4 + 2], g3 = Gj[w][tg * 4 + 3];
#pragma unroll
            for (int r = 0; r < 8; ++r) {
                float a = u.At[wi][ig * 8 + r];
                acc[r][0] += a * g0; acc[r][1] += a * g1;
                acc[r][2] += a * g2v; acc[r][3] += a * g3;
            }
        }
        __syncthreads();
    }
    bfu* Tj = T + ((size_t)(bl * N + j)) * N * H;
#pragma unroll
    for (int r = 0; r < 8; ++r) {
        ushort4 v;
        v.x = f2b(acc[r][0]); v.y = f2b(acc[r][1]);
        v.z = f2b(acc[r][2]); v.w = f2b(acc[r][3]);
        *(ushort4*)&Tj[(size_t)(ig * 8 + r) * H + tg * 4] = v;
    }
}

// ---------------- combine layer 2 + masked (i<j) reduction into part2[b][i][d]
__global__ __launch_bounds__(256) void combine2_kernel(const bfu* __restrict__ pair,
                                                       const float* __restrict__ W1,
                                                       const float* __restrict__ b1,
                                                       const bfu* __restrict__ T,
                                                       float* __restrict__ part2, int b0) {
    int bl = blockIdx.x / N, i = blockIdx.x % N;
    int b = b0 + bl;
    int t = threadIdx.x;
    __shared__ float Pi[N][H + 1];     // 33.3 KB
    __shared__ float W1s[H][H + 1];    // 16.6 KB
    __shared__ float red[4][H];
    {
        int k = t & 63; int j0 = t >> 6;
        const bfu* src = pair + ((size_t)(bl * N + i)) * N * H;
        for (int r = 0; r < 32; ++r) {
            int j = j0 + r * 4;
            Pi[j][k] = b2f(src[(size_t)j * H + k]);
        }
        for (int r = 0; r < 16; ++r) {
            int krow = j0 + r * 4;
            W1s[krow][k] = W1[(size_t)krow * H + k];
        }
    }
    __syncthreads();
    int d = t & 63; int jg = t >> 6;
    float accS[32];
    float bb = b1[d];
#pragma unroll
    for (int r = 0; r < 32; ++r) accS[r] = bb;
    for (int k = 0; k < H; ++k) {
        float w1v = W1s[k][d];
#pragma unroll
        for (int r = 0; r < 32; ++r) accS[r] += Pi[jg * 32 + r][k] * w1v;
    }
    const bfu* Tb = T + (size_t)bl * N * N * H;
    float esum = 0.f;
#pragma unroll 4
    for (int r = 0; r < 32; ++r) {
        int j = jg * 32 + r;
        float v = accS[r] + b2f(Tb[((size_t)j * N + i) * H + d]) + b2f(Tb[((size_t)i * N + j) * H + d]);
        v = fmaxf(v, 0.f);
        if (j > i) esum += v;
    }
    red[jg][d] = esum;
    __syncthreads();
    if (t < H)
        part2[((size_t)b * N + i) * H + t] = red[0][t] + red[1][t] + red[2][t] + red[3][t];
}

// ---------------- final head: out[b][c] = concat(emb1,emb2)@cw + cb
__global__ __launch_bounds__(64) void final_kernel(const float* __restrict__ emb1,
                                                   const float* __restrict__ emb2,
                                                   const float* __restrict__ cw,
                                                   const float* __restrict__ cb,
                                                   float* __restrict__ out) {
    int b = blockIdx.x;
    int c = threadIdx.x;
    if (c < C) {
        float acc = cb[c];
#pragma unroll 8
        for (int k = 0; k < H; ++k) acc += emb1[(size_t)b * H + k] * cw[(size_t)k * C + c];
#pragma unroll 8
        for (int k = 0; k < H; ++k) acc += emb2[(size_t)b * H + k] * cw[(size_t)(H + k) * C + c];
        out[(size_t)b * C + c] = acc;
    }
}

extern "C" void kernel_launch(void* const* d_in, const int* in_sizes, int n_in,
                              void* d_out, int out_size, void* d_ws, size_t ws_size,
                              hipStream_t stream) {
    const float* x    = (const float*)d_in[0];
    const float* adj  = (const float*)d_in[1];
    const float* w11  = (const float*)d_in[2];
    const float* b11  = (const float*)d_in[3];
    const float* w12  = (const float*)d_in[4];
    const float* b12  = (const float*)d_in[5];
    const float* w21  = (const float*)d_in[6];
    const float* b21  = (const float*)d_in[7];
    const float* w22  = (const float*)d_in[8];
    const float* b22  = (const float*)d_in[9];
    const float* p1w1 = (const float*)d_in[10];
    const float* p1b1 = (const float*)d_in[11];
    const float* p1w2 = (const float*)d_in[12];
    const float* p1b2 = (const float*)d_in[13];
    const float* p2w1 = (const float*)d_in[14];
    const float* p2b1 = (const float*)d_in[15];
    const float* p2w2 = (const float*)d_in[16];
    const float* p2b2 = (const float*)d_in[17];
    const float* cw   = (const float*)d_in[18];
    const float* cb   = (const float*)d_in[19];
    float* out = (float*)d_out;

    const size_t NBH = (size_t)B * N * H;            // 262144
    const size_t BIG = (size_t)N * N * H;            // per-batch pair-tensor elems (1,048,576)

    float* ws = (float*)d_ws;
    float* y1    = ws;                               // NBH
    float* y2    = y1 + NBH;                         // NBH
    float* h1    = y2 + NBH;                         // NBH
    float* h2    = h1 + NBH;                         // NBH
    float* U1    = h2 + NBH;                         // NBH
    float* V1    = U1 + NBH;                         // NBH
    float* U2    = V1 + NBH;                         // NBH
    float* V2    = U2 + NBH;                         // NBH
    float* part2 = V2 + NBH;                         // NBH
    float* emb1  = part2 + NBH;                      // B*H
    float* emb2  = emb1 + (size_t)B * H;             // B*H
    size_t smallBytes = (9 * NBH + 2 * (size_t)B * H) * sizeof(float);

    // pick largest batch-chunk whose two bf16 big buffers fit the workspace
    int CB = B;
    while (CB > 1 && smallBytes + 2ull * CB * BIG * sizeof(bfu) > ws_size) CB >>= 1;
    bfu* T    = (bfu*)((char*)d_ws + smallBytes);    // CB*BIG
    bfu* pair = T + (size_t)CB * BIG;                // CB*BIG

    dim3 rowGrid(B * N);

    // GNN layer 1
    lin_kernel<DD, true><<<rowGrid, 64, 0, stream>>>(x, w11, b11, y1);
    lin_kernel<DD, true><<<rowGrid, 64, 0, stream>>>(x, w12, b12, y2);
    agg_relu_kernel<<<rowGrid, 64, 0, stream>>>(y1, y2, adj, h1);
    // GNN layer 2
    lin_kernel<H, true><<<rowGrid, 64, 0, stream>>>(h1, w21, b21, y1);
    lin_kernel<H, true><<<rowGrid, 64, 0, stream>>>(h1, w22, b22, y2);
    agg_relu_kernel<<<rowGrid, 64, 0, stream>>>(y1, y2, adj, h2);
    // emb1
    rowsum_kernel<<<B, 64, 0, stream>>>(h2, emb1);
    // pair layer 1 decomposition: U/V for W1 (self) and W2 (g)
    lin_kernel<H, false><<<rowGrid, 64, 0, stream>>>(h2, p1w1, nullptr, U1);
    lin_kernel<H, false><<<rowGrid, 64, 0, stream>>>(h2, p1w1 + 64 * H, nullptr, V1);
    lin_kernel<H, false><<<rowGrid, 64, 0, stream>>>(h2, p1w2, nullptr, U2);
    lin_kernel<H, false><<<rowGrid, 64, 0, stream>>>(h2, p1w2 + 64 * H, nullptr, V2);

    // pair stages, chunked over batches to bound workspace footprint
    dim3 chunkGrid(CB * N);
    for (int b0 = 0; b0 < B; b0 += CB) {
        t1_kernel<<<chunkGrid, 256, 0, stream>>>(U2, V2, adj, p1w2 + 128 * H, p1b2, T, b0);
        combine1_kernel<<<chunkGrid, 256, 0, stream>>>(U1, V1, adj, p1w1 + 128 * H, p1b1, T, pair, b0);
        t2_kernel<<<chunkGrid, 256, 0, stream>>>(pair, p2w2, p2b2, adj, T, b0);
        combine2_kernel<<<chunkGrid, 256, 0, stream>>>(pair, p2w1, p2b1, T, part2, b0);
    }

    // emb2[b][d] = sum_i part2[b][i][d]
    rowsum_kernel<<<B, 64, 0, stream>>>(part2, emb2);
    // classifier head
    final_kernel<<<B, 64, 0, stream>>>(emb1, emb2, cw, cb, out);
}

// Round 3
// 260.053 us; speedup vs baseline: 3.1744x; 3.1744x over previous
//
#include <hip/hip_runtime.h>

#define B 32
#define N 128
#define DD 32
#define H 64
#define C 10

typedef unsigned short bfu;   // raw bf16 storage
typedef __attribute__((ext_vector_type(8))) short bf16x8;  // 8 bf16 (4 VGPRs)
typedef __attribute__((ext_vector_type(4))) float f32x4;   // MFMA accumulator

#define MFMA16 __builtin_amdgcn_mfma_f32_16x16x32_bf16

__device__ __forceinline__ float b2f(bfu v) {
    union { unsigned u; float f; } x; x.u = ((unsigned)v) << 16; return x.f;
}
__device__ __forceinline__ bfu f2b(float f) {
    union { float f; unsigned u; } x; x.f = f;
    unsigned r = x.u + 0x7fffu + ((x.u >> 16) & 1u);   // RNE
    return (bfu)(r >> 16);
}
__device__ __forceinline__ float lo2f(unsigned u) {
    union { unsigned x; float f; } c; c.x = u << 16; return c.f;
}
__device__ __forceinline__ float hi2f(unsigned u) {
    union { unsigned x; float f; } c; c.x = u & 0xffff0000u; return c.f;
}
__device__ __forceinline__ void up8(uint4 u, float* f) {
    f[0] = lo2f(u.x); f[1] = hi2f(u.x); f[2] = lo2f(u.y); f[3] = hi2f(u.y);
    f[4] = lo2f(u.z); f[5] = hi2f(u.z); f[6] = lo2f(u.w); f[7] = hi2f(u.w);
}
__device__ __forceinline__ unsigned pk2(float a, float b) {
    return (unsigned)f2b(a) | ((unsigned)f2b(b) << 16);
}

// ---------------- prep: ac_bf16[b][i][w] = bf16(adj * (1-I))
__global__ __launch_bounds__(256) void prep_ac(const float* __restrict__ adj,
                                               bfu* __restrict__ acb) {
    int idx = blockIdx.x * 256 + threadIdx.x;          // one float4 (4 elems)
    float4 v = ((const float4*)adj)[idx];
    int e0 = idx * 4;
    int w = e0 & 127;
    int i = (e0 >> 7) & 127;
    ushort4 o;
    o.x = f2b((i == w    ) ? 0.f : v.x);
    o.y = f2b((i == w + 1) ? 0.f : v.y);
    o.z = f2b((i == w + 2) ? 0.f : v.z);
    o.w = f2b((i == w + 3) ? 0.f : v.w);
    ((ushort4*)acb)[idx] = o;
}

// ---------------- prep: transposed bf16 weights Wt[d][k] = W[k][d] (64x64)
__global__ __launch_bounds__(256) void prep_wt(const float* __restrict__ W1,
                                               const float* __restrict__ W2,
                                               bfu* __restrict__ W1t,
                                               bfu* __restrict__ W2t) {
    const float* Wi = blockIdx.x ? W2 : W1;
    bfu* Wo = blockIdx.x ? W2t : W1t;
    int t = threadIdx.x; int d = t & 63, k0 = (t >> 6) * 16;
#pragma unroll
    for (int kk = 0; kk < 16; ++kk)
        Wo[d * 64 + k0 + kk] = f2b(Wi[(k0 + kk) * 64 + d]);
}

// ---------------- batched small linears: 4 rows/block, up to 4 outputs
struct P4 { const float* W[4]; const float* bia[4]; float* o[4]; };

template<int K, int NO, bool BIAS>
__global__ __launch_bounds__(256) void lin_multi(const float* __restrict__ in, P4 p) {
    int row0 = blockIdx.x * 4;
    int t = threadIdx.x; int g = t >> 6, c = t & 63;
    __shared__ float xs[4][K];
    if (t < 4 * K) xs[t / K][t % K] = in[(size_t)row0 * K + t];
    __syncthreads();
    int row = row0 + g;
#pragma unroll
    for (int o = 0; o < NO; ++o) {
        const float* W = p.W[o];
        float acc = BIAS ? p.bia[o][c] : 0.f;
#pragma unroll 8
        for (int k = 0; k < K; ++k) acc += xs[g][k] * W[k * H + c];
        p.o[o][(size_t)row * H + c] = acc;
    }
}

// ---------------- h = relu(y1 + adj @ y2), 4 rows per block
__global__ __launch_bounds__(256) void agg_relu4(const float* __restrict__ y1,
                                                 const float* __restrict__ y2,
                                                 const float* __restrict__ adj,
                                                 float* __restrict__ hout) {
    int b = blockIdx.x >> 5, i0 = (blockIdx.x & 31) * 4;
    int t = threadIdx.x; int g = t >> 6, d = t & 63;
    __shared__ float arow[4][N];
    ((float*)arow)[t]       = adj[((size_t)b * N + i0) * N + t];
    ((float*)arow)[t + 256] = adj[((size_t)b * N + i0) * N + t + 256];
    __syncthreads();
    const float* y2b = y2 + (size_t)b * N * H;
    int i = i0 + g;
    float acc = y1[((size_t)b * N + i) * H + d];
#pragma unroll 8
    for (int j = 0; j < N; ++j) acc += arow[g][j] * y2b[(size_t)j * H + d];
    hout[((size_t)b * N + i) * H + d] = fmaxf(acc, 0.f);
}

// ---------------- sum over middle axis: out[b][d] = sum_n in[b][n][d]
__global__ __launch_bounds__(64) void rowsum_kernel(const float* __restrict__ in,
                                                    float* __restrict__ out) {
    int b = blockIdx.x;
    int d = threadIdx.x;
    float acc = 0.f;
#pragma unroll 8
    for (int n = 0; n < N; ++n) acc += in[((size_t)b * N + n) * H + d];
    out[(size_t)b * H + d] = acc;
}

// ---------------- t1: T[bl,j,i,d] = sum_w ac[b,i,w]*G[j,w,d]  via MFMA
// G[j,w,d] = U2[min(j,w),d] + V2[max(j,w),d] + ac[j,w]*wl[d] + bv[d]
__global__ __launch_bounds__(256) void t1_mfma(const float* __restrict__ U2,
                                               const float* __restrict__ V2,
                                               const bfu* __restrict__ acb,
                                               const float* __restrict__ wl,
                                               const float* __restrict__ bv,
                                               bfu* __restrict__ T, int b0) {
    int bl = blockIdx.x >> 7, j = blockIdx.x & 127;
    int b = b0 + bl;
    int t = threadIdx.x, lane = t & 63, wid = t >> 6;
    int l16 = lane & 15, g4 = lane >> 4;
    __shared__ bfu lds[128 * 72];   // Gt[64][136] (build+GEMM) then stage[128][72]
    {
        const float* U2b = U2 + (size_t)b * N * H;
        const float* V2b = V2 + (size_t)b * N * H;
        const bfu* arow = acb + ((size_t)b * N + j) * N;
        int w0 = lane, w1 = lane + 64;
        float a0 = b2f(arow[w0]), a1 = b2f(arow[w1]);
        int mn0 = min(j, w0) * H, mx0 = max(j, w0) * H;
        int mn1 = min(j, w1) * H, mx1 = max(j, w1) * H;
#pragma unroll 4
        for (int dd = 0; dd < 16; ++dd) {
            int d = wid * 16 + dd;
            float wld = wl[d], bbd = bv[d];
            lds[d * 136 + w0] = f2b(U2b[mn0 + d] + V2b[mx0 + d] + a0 * wld + bbd);
            lds[d * 136 + w1] = f2b(U2b[mn1 + d] + V2b[mx1 + d] + a1 * wld + bbd);
        }
    }
    __syncthreads();
    f32x4 acc[2][4];
#pragma unroll
    for (int m = 0; m < 2; ++m)
#pragma unroll
        for (int n = 0; n < 4; ++n) acc[m][n] = (f32x4){0.f, 0.f, 0.f, 0.f};
    const bfu* Ab = acb + (size_t)b * N * N;
#pragma unroll
    for (int ks = 0; ks < 4; ++ks) {
        int k0 = ks * 32 + g4 * 8;
        bf16x8 bfr[4];
#pragma unroll
        for (int n = 0; n < 4; ++n)
            bfr[n] = *(const bf16x8*)&lds[(l16 + 16 * n) * 136 + k0];
#pragma unroll
        for (int m = 0; m < 2; ++m) {
            int i = wid * 32 + m * 16 + l16;
            bf16x8 afr = *(const bf16x8*)&Ab[(size_t)i * N + k0];
#pragma unroll
            for (int n = 0; n < 4; ++n)
                acc[m][n] = MFMA16(afr, bfr[n], acc[m][n], 0, 0, 0);
        }
    }
    __syncthreads();
#pragma unroll
    for (int m = 0; m < 2; ++m)
#pragma unroll
        for (int n = 0; n < 4; ++n)
#pragma unroll
            for (int r = 0; r < 4; ++r)
                lds[(wid * 32 + m * 16 + g4 * 4 + r) * 72 + l16 + 16 * n] = f2b(acc[m][n][r]);
    __syncthreads();
    {
        int i = t >> 1, half = t & 1;
        const uint4* src = (const uint4*)&lds[i * 72 + half * 32];
        uint4* dst = (uint4*)(T + (((size_t)bl * N + j) * N + i) * H + half * 32);
        dst[0] = src[0]; dst[1] = src[1]; dst[2] = src[2]; dst[3] = src[3];
    }
}

// ---------------- combine1: pair[bl,i,j,d] = relu(self + T[bl,j,i,d] + T[bl,i,j,d])
__global__ __launch_bounds__(256) void combine1_v(const float* __restrict__ U1,
                                                  const float* __restrict__ V1,
                                                  const bfu* __restrict__ acb,
                                                  const float* __restrict__ wl,
                                                  const float* __restrict__ bv,
                                                  const bfu* __restrict__ T,
                                                  bfu* __restrict__ pair, int b0) {
    int bl = blockIdx.x >> 7, i = blockIdx.x & 127;
    int b = b0 + bl;
    int t = threadIdx.x;
    int dc = t & 7, jg = t >> 3, d0 = dc * 8;
    const float* U1b = U1 + (size_t)b * N * H;
    const float* V1b = V1 + (size_t)b * N * H;
    const bfu* arow = acb + ((size_t)b * N + i) * N;
    const bfu* Tb = T + (size_t)bl * N * N * H;
    bfu* pr = pair + ((size_t)bl * N + i) * (size_t)(N * H);
    float wlv[8], bbv[8];
#pragma unroll
    for (int e = 0; e < 8; ++e) { wlv[e] = wl[d0 + e]; bbv[e] = bv[d0 + e]; }
#pragma unroll
    for (int r = 0; r < 4; ++r) {
        int j = jg + r * 32;
        float a = b2f(arow[j]);
        int mn = min(i, j), mx = max(i, j);
        float4 ua = *(const float4*)(U1b + mn * H + d0);
        float4 ub = *(const float4*)(U1b + mn * H + d0 + 4);
        float4 va = *(const float4*)(V1b + mx * H + d0);
        float4 vb = *(const float4*)(V1b + mx * H + d0 + 4);
        float uu[8] = {ua.x, ua.y, ua.z, ua.w, ub.x, ub.y, ub.z, ub.w};
        float vv[8] = {va.x, va.y, va.z, va.w, vb.x, vb.y, vb.z, vb.w};
        float tj[8], ti[8];
        up8(*(const uint4*)&Tb[((size_t)j * N + i) * H + d0], tj);
        up8(*(const uint4*)&Tb[((size_t)i * N + j) * H + d0], ti);
        float o[8];
#pragma unroll
        for (int e = 0; e < 8; ++e)
            o[e] = fmaxf(uu[e] + vv[e] + a * wlv[e] + bbv[e] + tj[e] + ti[e], 0.f);
        uint4 ov;
        ov.x = pk2(o[0], o[1]); ov.y = pk2(o[2], o[3]);
        ov.z = pk2(o[4], o[5]); ov.w = pk2(o[6], o[7]);
        *(uint4*)&pr[(size_t)j * H + d0] = ov;
    }
}

// ---------------- t2: G2 = pair[bl,j]@W2 + b2 ; T[bl,j,i,d] = sum_w ac[i,w]*G2[w,d]
__global__ __launch_bounds__(256) void t2_mfma(const bfu* __restrict__ pair,
                                               const bfu* __restrict__ W2t,
                                               const float* __restrict__ bv,
                                               const bfu* __restrict__ acb,
                                               bfu* __restrict__ T, int b0) {
    int bl = blockIdx.x >> 7, j = blockIdx.x & 127;
    int b = b0 + bl;
    int t = threadIdx.x, lane = t & 63, wid = t >> 6;
    int l16 = lane & 15, g4 = lane >> 4;
    __shared__ bfu lds[128 * 72];
    f32x4 acc[2][4];
#pragma unroll
    for (int m = 0; m < 2; ++m)
#pragma unroll
        for (int n = 0; n < 4; ++n) acc[m][n] = (f32x4){0.f, 0.f, 0.f, 0.f};
    // phase A: G2 = P @ W2 + b2   (P = pair[bl,j], 128x64)
    const bfu* Prow = pair + ((size_t)bl * N + j) * (size_t)(N * H);
#pragma unroll
    for (int ks = 0; ks < 2; ++ks) {
        int k0 = ks * 32 + g4 * 8;
        bf16x8 bw[4];
#pragma unroll
        for (int n = 0; n < 4; ++n)
            bw[n] = *(const bf16x8*)&W2t[(l16 + 16 * n) * 64 + k0];
#pragma unroll
        for (int m = 0; m < 2; ++m) {
            int w = wid * 32 + m * 16 + l16;
            bf16x8 af = *(const bf16x8*)&Prow[(size_t)w * H + k0];
#pragma unroll
            for (int n = 0; n < 4; ++n)
                acc[m][n] = MFMA16(af, bw[n], acc[m][n], 0, 0, 0);
        }
    }
    {
        float bb[4];
#pragma unroll
        for (int n = 0; n < 4; ++n) bb[n] = bv[l16 + 16 * n];
#pragma unroll
        for (int m = 0; m < 2; ++m)
#pragma unroll
            for (int n = 0; n < 4; ++n)
#pragma unroll
                for (int r = 0; r < 4; ++r)
                    lds[(l16 + 16 * n) * 136 + wid * 32 + m * 16 + g4 * 4 + r] =
                        f2b(acc[m][n][r] + bb[n]);
    }
    __syncthreads();
    // phase B: T = Ac @ G2
#pragma unroll
    for (int m = 0; m < 2; ++m)
#pragma unroll
        for (int n = 0; n < 4; ++n) acc[m][n] = (f32x4){0.f, 0.f, 0.f, 0.f};
    const bfu* Ab = acb + (size_t)b * N * N;
#pragma unroll
    for (int ks = 0; ks < 4; ++ks) {
        int k0 = ks * 32 + g4 * 8;
        bf16x8 bfr[4];
#pragma unroll
        for (int n = 0; n < 4; ++n)
            bfr[n] = *(const bf16x8*)&lds[(l16 + 16 * n) * 136 + k0];
#pragma unroll
        for (int m = 0; m < 2; ++m) {
            int i = wid * 32 + m * 16 + l16;
            bf16x8 afr = *(const bf16x8*)&Ab[(size_t)i * N + k0];
#pragma unroll
            for (int n = 0; n < 4; ++n)
                acc[m][n] = MFMA16(afr, bfr[n], acc[m][n], 0, 0, 0);
        }
    }
    __syncthreads();
#pragma unroll
    for (int m = 0; m < 2; ++m)
#pragma unroll
        for (int n = 0; n < 4; ++n)
#pragma unroll
            for (int r = 0; r < 4; ++r)
                lds[(wid * 32 + m * 16 + g4 * 4 + r) * 72 + l16 + 16 * n] = f2b(acc[m][n][r]);
    __syncthreads();
    {
        int i = t >> 1, half = t & 1;
        const uint4* src = (const uint4*)&lds[i * 72 + half * 32];
        uint4* dst = (uint4*)(T + (((size_t)bl * N + j) * N + i) * H + half * 32);
        dst[0] = src[0]; dst[1] = src[1]; dst[2] = src[2]; dst[3] = src[3];
    }
}

// ---------------- combine2: S = pair[bl,i]@W1 + b1 ; part2[b,i,d] = sum_{j>i} relu(S+T+T')
__global__ __launch_bounds__(256) void combine2_v(const bfu* __restrict__ pair,
                                                  const bfu* __restrict__ W1t,
                                                  const float* __restrict__ bv,
                                                  const bfu* __restrict__ T,
                                                  float* __restrict__ part2, int b0) {
    int bl = blockIdx.x >> 7, i = blockIdx.x & 127;
    int b = b0 + bl;
    int t = threadIdx.x, lane = t & 63, wid = t >> 6;
    int l16 = lane & 15, g4 = lane >> 4;
    __shared__ float S[128 * 68];   // 34.8 KB; reused as red[32][64] in reduction
    f32x4 acc[2][4];
#pragma unroll
    for (int m = 0; m < 2; ++m)
#pragma unroll
        for (int n = 0; n < 4; ++n) acc[m][n] = (f32x4){0.f, 0.f, 0.f, 0.f};
    const bfu* Prow = pair + ((size_t)bl * N + i) * (size_t)(N * H);
#pragma unroll
    for (int ks = 0; ks < 2; ++ks) {
        int k0 = ks * 32 + g4 * 8;
        bf16x8 bw[4];
#pragma unroll
        for (int n = 0; n < 4; ++n)
            bw[n] = *(const bf16x8*)&W1t[(l16 + 16 * n) * 64 + k0];
#pragma unroll
        for (int m = 0; m < 2; ++m) {
            int jr = wid * 32 + m * 16 + l16;
            bf16x8 af = *(const bf16x8*)&Prow[(size_t)jr * H + k0];
#pragma unroll
            for (int n = 0; n < 4; ++n)
                acc[m][n] = MFMA16(af, bw[n], acc[m][n], 0, 0, 0);
        }
    }
    {
        float bb[4];
#pragma unroll
        for (int n = 0; n < 4; ++n) bb[n] = bv[l16 + 16 * n];
#pragma unroll
        for (int m = 0; m < 2; ++m)
#pragma unroll
            for (int n = 0; n < 4; ++n)
#pragma unroll
                for (int r = 0; r < 4; ++r)
                    S[(wid * 32 + m * 16 + g4 * 4 + r) * 68 + l16 + 16 * n] =
                        acc[m][n][r] + bb[n];
    }
    __syncthreads();
    // phase 2: masked relu-sum over j>i
    int dc = t & 7, jg = t >> 3, d0 = dc * 8;
    float ps[8];
#pragma unroll
    for (int e = 0; e < 8; ++e) ps[e] = 0.f;
    const bfu* Tb = T + (size_t)bl * N * N * H;
#pragma unroll
    for (int r = 0; r < 4; ++r) {
        int j = jg + r * 32;
        if (j > i) {
            float ti[8], tj[8];
            up8(*(const uint4*)&Tb[((size_t)i * N + j) * H + d0], ti);
            up8(*(const uint4*)&Tb[((size_t)j * N + i) * H + d0], tj);
            const float* sr = &S[j * 68 + d0];
#pragma unroll
            for (int e = 0; e < 8; ++e)
                ps[e] += fmaxf(sr[e] + ti[e] + tj[e], 0.f);
        }
    }
    __syncthreads();
    float* red = S;
#pragma unroll
    for (int e = 0; e < 8; ++e) red[jg * 64 + d0 + e] = ps[e];
    __syncthreads();
    if (t < 64) {
        float s = 0.f;
#pragma unroll 8
        for (int g = 0; g < 32; ++g) s += red[g * 64 + t];
        part2[((size_t)b * N + i) * H + t] = s;
    }
}

// ---------------- final head
__global__ __launch_bounds__(64) void final_kernel(const float* __restrict__ emb1,
                                                   const float* __restrict__ emb2,
                                                   const float* __restrict__ cw,
                                                   const float* __restrict__ cb,
                                                   float* __restrict__ out) {
    int b = blockIdx.x;
    int c = threadIdx.x;
    if (c < C) {
        float acc = cb[c];
#pragma unroll 8
        for (int k = 0; k < H; ++k) acc += emb1[(size_t)b * H + k] * cw[(size_t)k * C + c];
#pragma unroll 8
        for (int k = 0; k < H; ++k) acc += emb2[(size_t)b * H + k] * cw[(size_t)(H + k) * C + c];
        out[(size_t)b * C + c] = acc;
    }
}

extern "C" void kernel_launch(void* const* d_in, const int* in_sizes, int n_in,
                              void* d_out, int out_size, void* d_ws, size_t ws_size,
                              hipStream_t stream) {
    const float* x    = (const float*)d_in[0];
    const float* adj  = (const float*)d_in[1];
    const float* w11  = (const float*)d_in[2];
    const float* b11  = (const float*)d_in[3];
    const float* w12  = (const float*)d_in[4];
    const float* b12  = (const float*)d_in[5];
    const float* w21  = (const float*)d_in[6];
    const float* b21  = (const float*)d_in[7];
    const float* w22  = (const float*)d_in[8];
    const float* b22  = (const float*)d_in[9];
    const float* p1w1 = (const float*)d_in[10];
    const float* p1b1 = (const float*)d_in[11];
    const float* p1w2 = (const float*)d_in[12];
    const float* p1b2 = (const float*)d_in[13];
    const float* p2w1 = (const float*)d_in[14];
    const float* p2b1 = (const float*)d_in[15];
    const float* p2w2 = (const float*)d_in[16];
    const float* p2b2 = (const float*)d_in[17];
    const float* cw   = (const float*)d_in[18];
    const float* cb   = (const float*)d_in[19];
    float* out = (float*)d_out;

    const size_t NBH = (size_t)B * N * H;            // 262144
    const size_t BIG = (size_t)N * N * H;            // 1,048,576

    float* ws = (float*)d_ws;
    float* y1    = ws;                               // NBH
    float* y2    = y1 + NBH;
    float* h1    = y2 + NBH;
    float* h2    = h1 + NBH;
    float* U1    = h2 + NBH;
    float* V1    = U1 + NBH;
    float* U2    = V1 + NBH;
    float* V2    = U2 + NBH;
    float* part2 = V2 + NBH;
    float* emb1  = part2 + NBH;                      // B*H
    float* emb2  = emb1 + (size_t)B * H;             // B*H
    size_t smallBytes = (9 * NBH + 2 * (size_t)B * H) * sizeof(float);   // 9,453,568 B

    bfu* acb = (bfu*)((char*)d_ws + smallBytes);     // B*N*N bf16 = 1 MB
    size_t acBytes = (size_t)B * N * N * sizeof(bfu);
    bfu* W1t = acb + (size_t)B * N * N;              // 64*64
    bfu* W2t = W1t + 64 * 64;
    size_t wtBytes = 2 * 64 * 64 * sizeof(bfu);

    // pick largest batch-chunk whose two bf16 big buffers fit the workspace
    int CB = B;
    while (CB > 1 && smallBytes + acBytes + wtBytes + 2ull * CB * BIG * sizeof(bfu) > ws_size)
        CB >>= 1;
    bfu* T    = (bfu*)((char*)d_ws + smallBytes + acBytes + wtBytes);    // CB*BIG
    bfu* pairb = T + (size_t)CB * BIG;                                   // CB*BIG

    // prep
    prep_ac<<<dim3(B * N * N / 1024), 256, 0, stream>>>(adj, acb);
    prep_wt<<<dim3(2), 256, 0, stream>>>(p2w1, p2w2, W1t, W2t);

    dim3 quadGrid(B * N / 4);
    // GNN layer 1
    {
        P4 p{{w11, w12}, {b11, b12}, {y1, y2}};
        lin_multi<DD, 2, true><<<quadGrid, 256, 0, stream>>>(x, p);
    }
    agg_relu4<<<quadGrid, 256, 0, stream>>>(y1, y2, adj, h1);
    // GNN layer 2
    {
        P4 p{{w21, w22}, {b21, b22}, {y1, y2}};
        lin_multi<H, 2, true><<<quadGrid, 256, 0, stream>>>(h1, p);
    }
    agg_relu4<<<quadGrid, 256, 0, stream>>>(y1, y2, adj, h2);
    // emb1
    rowsum_kernel<<<B, 64, 0, stream>>>(h2, emb1);
    // U/V projections of h2
    {
        P4 p{{p1w1, p1w1 + 64 * H, p1w2, p1w2 + 64 * H},
             {nullptr, nullptr, nullptr, nullptr},
             {U1, V1, U2, V2}};
        lin_multi<H, 4, false><<<quadGrid, 256, 0, stream>>>(h2, p);
    }

    // pair stages, chunked over batches
    for (int b0 = 0; b0 < B; b0 += CB) {
        dim3 cg(CB * N);
        t1_mfma<<<cg, 256, 0, stream>>>(U2, V2, acb, p1w2 + 128 * H, p1b2, T, b0);
        combine1_v<<<cg, 256, 0, stream>>>(U1, V1, acb, p1w1 + 128 * H, p1b1, T, pairb, b0);
        t2_mfma<<<cg, 256, 0, stream>>>(pairb, W2t, p2b2, acb, T, b0);
        combine2_v<<<cg, 256, 0, stream>>>(pairb, W1t, p2b1, T, part2, b0);
    }

    rowsum_kernel<<<B, 64, 0, stream>>>(part2, emb2);
    final_kernel<<<B, 64, 0, stream>>>(emb1, emb2, cw, cb, out);
}

// Round 4
// 253.692 us; speedup vs baseline: 3.2540x; 1.0251x over previous
//
#include <hip/hip_runtime.h>

#define B 32
#define N 128
#define DD 32
#define H 64
#define C 10

typedef unsigned short bfu;   // raw bf16 storage
typedef __attribute__((ext_vector_type(8))) short bf16x8;  // 8 bf16 (4 VGPRs)
typedef __attribute__((ext_vector_type(4))) float f32x4;   // MFMA accumulator

#define MFMA16 __builtin_amdgcn_mfma_f32_16x16x32_bf16

__device__ __forceinline__ float b2f(bfu v) {
    union { unsigned u; float f; } x; x.u = ((unsigned)v) << 16; return x.f;
}
__device__ __forceinline__ bfu f2b(float f) {
    union { float f; unsigned u; } x; x.f = f;
    unsigned r = x.u + 0x7fffu + ((x.u >> 16) & 1u);   // RNE
    return (bfu)(r >> 16);
}
__device__ __forceinline__ float lo2f(unsigned u) {
    union { unsigned x; float f; } c; c.x = u << 16; return c.f;
}
__device__ __forceinline__ float hi2f(unsigned u) {
    union { unsigned x; float f; } c; c.x = u & 0xffff0000u; return c.f;
}
__device__ __forceinline__ void up8(uint4 u, float* f) {
    f[0] = lo2f(u.x); f[1] = hi2f(u.x); f[2] = lo2f(u.y); f[3] = hi2f(u.y);
    f[4] = lo2f(u.z); f[5] = hi2f(u.z); f[6] = lo2f(u.w); f[7] = hi2f(u.w);
}
__device__ __forceinline__ unsigned pk2(float a, float b) {
    return (unsigned)f2b(a) | ((unsigned)f2b(b) << 16);
}

// ---------------- prep: ac_bf16[b][i][w] = bf16(adj * (1-I))
__global__ __launch_bounds__(256) void prep_ac(const float* __restrict__ adj,
                                               bfu* __restrict__ acb) {
    int idx = blockIdx.x * 256 + threadIdx.x;          // one float4 (4 elems)
    float4 v = ((const float4*)adj)[idx];
    int e0 = idx * 4;
    int w = e0 & 127;
    int i = (e0 >> 7) & 127;
    ushort4 o;
    o.x = f2b((i == w    ) ? 0.f : v.x);
    o.y = f2b((i == w + 1) ? 0.f : v.y);
    o.z = f2b((i == w + 2) ? 0.f : v.z);
    o.w = f2b((i == w + 3) ? 0.f : v.w);
    ((ushort4*)acb)[idx] = o;
}

// ---------------- prep: transposed bf16 weights Wt[d][k] = W[k][d] (64x64)
__global__ __launch_bounds__(256) void prep_wt(const float* __restrict__ W1,
                                               const float* __restrict__ W2,
                                               bfu* __restrict__ W1t,
                                               bfu* __restrict__ W2t) {
    const float* Wi = blockIdx.x ? W2 : W1;
    bfu* Wo = blockIdx.x ? W2t : W1t;
    int t = threadIdx.x; int d = t & 63, k0 = (t >> 6) * 16;
#pragma unroll
    for (int kk = 0; kk < 16; ++kk)
        Wo[d * 64 + k0 + kk] = f2b(Wi[(k0 + kk) * 64 + d]);
}

// ---------------- batched small linears: 4 rows/block, up to 4 outputs
struct P4 { const float* W[4]; const float* bia[4]; float* o[4]; };

template<int K, int NO, bool BIAS>
__global__ __launch_bounds__(256) void lin_multi(const float* __restrict__ in, P4 p) {
    int row0 = blockIdx.x * 4;
    int t = threadIdx.x; int g = t >> 6, c = t & 63;
    __shared__ float xs[4][K];
    if (t < 4 * K) xs[t / K][t % K] = in[(size_t)row0 * K + t];
    __syncthreads();
    int row = row0 + g;
#pragma unroll
    for (int o = 0; o < NO; ++o) {
        const float* W = p.W[o];
        float acc = BIAS ? p.bia[o][c] : 0.f;
#pragma unroll 8
        for (int k = 0; k < K; ++k) acc += xs[g][k] * W[k * H + c];
        p.o[o][(size_t)row * H + c] = acc;
    }
}

// ---------------- h = relu(y1 + adj @ y2), 4 rows per block
__global__ __launch_bounds__(256) void agg_relu4(const float* __restrict__ y1,
                                                 const float* __restrict__ y2,
                                                 const float* __restrict__ adj,
                                                 float* __restrict__ hout) {
    int b = blockIdx.x >> 5, i0 = (blockIdx.x & 31) * 4;
    int t = threadIdx.x; int g = t >> 6, d = t & 63;
    __shared__ float arow[4][N];
    ((float*)arow)[t]       = adj[((size_t)b * N + i0) * N + t];
    ((float*)arow)[t + 256] = adj[((size_t)b * N + i0) * N + t + 256];
    __syncthreads();
    const float* y2b = y2 + (size_t)b * N * H;
    int i = i0 + g;
    float acc = y1[((size_t)b * N + i) * H + d];
#pragma unroll 8
    for (int j = 0; j < N; ++j) acc += arow[g][j] * y2b[(size_t)j * H + d];
    hout[((size_t)b * N + i) * H + d] = fmaxf(acc, 0.f);
}

// ---------------- sum over middle axis: out[b][d] = sum_n in[b][n][d]
__global__ __launch_bounds__(64) void rowsum_kernel(const float* __restrict__ in,
                                                    float* __restrict__ out) {
    int b = blockIdx.x;
    int d = threadIdx.x;
    float acc = 0.f;
#pragma unroll 8
    for (int n = 0; n < N; ++n) acc += in[((size_t)b * N + n) * H + d];
    out[(size_t)b * H + d] = acc;
}

// ---------------- t1: T1[bl,j,i,d] = sum_w ac[b,i,w]*G[j,w,d]  via MFMA
// G[j,w,d] = U2[min(j,w),d] + V2[max(j,w),d] + ac[j,w]*wl[d] + bv[d]
__global__ __launch_bounds__(256) void t1_mfma(const float* __restrict__ U2,
                                               const float* __restrict__ V2,
                                               const bfu* __restrict__ acb,
                                               const float* __restrict__ wl,
                                               const float* __restrict__ bv,
                                               bfu* __restrict__ T, int b0) {
    int bl = blockIdx.x >> 7, j = blockIdx.x & 127;
    int b = b0 + bl;
    int t = threadIdx.x, lane = t & 63, wid = t >> 6;
    int l16 = lane & 15, g4 = lane >> 4;
    __shared__ bfu lds[128 * 72];   // Gt[64][136] (build+GEMM) then stage[128][72]
    {
        // coalesced G-build: lane -> d, wave-uniform w; j-row cached in regs
        int d = lane;
        const float* U2b = U2 + (size_t)b * N * H;
        const float* V2b = V2 + (size_t)b * N * H;
        const bfu* arow = acb + ((size_t)b * N + j) * N;
        float Uj = U2b[j * H + d], Vj = V2b[j * H + d];
        float wld = wl[d], bvd = bv[d];
#pragma unroll
        for (int p = 0; p < 4; ++p) {
            int w0 = p * 32 + wid * 8;
            unsigned q[4];
#pragma unroll
            for (int rr = 0; rr < 4; ++rr) {
                float g01[2];
#pragma unroll
                for (int hh = 0; hh < 2; ++hh) {
                    int w = w0 + rr * 2 + hh;
                    float a = b2f(arow[w]);
                    float rvar = (w < j) ? U2b[w * H + d] : V2b[w * H + d];
                    float base = (w < j) ? Vj : Uj;
                    g01[hh] = rvar + base + a * wld + bvd;
                }
                q[rr] = pk2(g01[0], g01[1]);
            }
            *(uint4*)&lds[d * 136 + w0] = make_uint4(q[0], q[1], q[2], q[3]);
        }
    }
    __syncthreads();
    f32x4 acc[2][4];
#pragma unroll
    for (int m = 0; m < 2; ++m)
#pragma unroll
        for (int n = 0; n < 4; ++n) acc[m][n] = (f32x4){0.f, 0.f, 0.f, 0.f};
    const bfu* Ab = acb + (size_t)b * N * N;
#pragma unroll
    for (int ks = 0; ks < 4; ++ks) {
        int k0 = ks * 32 + g4 * 8;
        bf16x8 bfr[4];
#pragma unroll
        for (int n = 0; n < 4; ++n)
            bfr[n] = *(const bf16x8*)&lds[(l16 + 16 * n) * 136 + k0];
#pragma unroll
        for (int m = 0; m < 2; ++m) {
            int i = wid * 32 + m * 16 + l16;
            bf16x8 afr = *(const bf16x8*)&Ab[(size_t)i * N + k0];
#pragma unroll
            for (int n = 0; n < 4; ++n)
                acc[m][n] = MFMA16(afr, bfr[n], acc[m][n], 0, 0, 0);
        }
    }
    __syncthreads();
#pragma unroll
    for (int m = 0; m < 2; ++m)
#pragma unroll
        for (int n = 0; n < 4; ++n)
#pragma unroll
            for (int r = 0; r < 4; ++r)
                lds[(wid * 32 + m * 16 + g4 * 4 + r) * 72 + l16 + 16 * n] = f2b(acc[m][n][r]);
    __syncthreads();
    {
        int i = t >> 1, half = t & 1;
        const uint4* src = (const uint4*)&lds[i * 72 + half * 32];
        uint4* dst = (uint4*)(T + (((size_t)bl * N + j) * N + i) * H + half * 32);
        dst[0] = src[0]; dst[1] = src[1]; dst[2] = src[2]; dst[3] = src[3];
    }
}

// ---------------- shared P-row builder: pair[bl,c,w,:] fragment (8 bf16 at d0=ks*32+g4*8)
// P[w][d] = relu(U1[min(c,w),d] + V1[max(c,w),d] + ac[c,w]*wl1[d] + bv1[d]
//               + T1[bl,c,w,d] + T1[bl,w,c,d])
__device__ __forceinline__ bf16x8 build_pa(const float* U1b, const float* V1b,
                                           float a, const float* wl1,
                                           const float* bv1, const bfu* T1b,
                                           int c, int w, int d0) {
    int mn = min(c, w), mx = max(c, w);
    float u[8], v[8], tc[8], tw[8], wv[8], bb[8];
    *(float4*)&u[0] = *(const float4*)(U1b + mn * H + d0);
    *(float4*)&u[4] = *(const float4*)(U1b + mn * H + d0 + 4);
    *(float4*)&v[0] = *(const float4*)(V1b + mx * H + d0);
    *(float4*)&v[4] = *(const float4*)(V1b + mx * H + d0 + 4);
    up8(*(const uint4*)&T1b[((size_t)c * N + w) * H + d0], tc);
    up8(*(const uint4*)&T1b[((size_t)w * N + c) * H + d0], tw);
    *(float4*)&wv[0] = *(const float4*)(wl1 + d0);
    *(float4*)&wv[4] = *(const float4*)(wl1 + d0 + 4);
    *(float4*)&bb[0] = *(const float4*)(bv1 + d0);
    *(float4*)&bb[4] = *(const float4*)(bv1 + d0 + 4);
    union { bf16x8 f; unsigned q[4]; } pk;
#pragma unroll
    for (int e = 0; e < 4; ++e) {
        float p0 = fmaxf(u[2*e]   + v[2*e]   + a * wv[2*e]   + bb[2*e]   + tc[2*e]   + tw[2*e],   0.f);
        float p1 = fmaxf(u[2*e+1] + v[2*e+1] + a * wv[2*e+1] + bb[2*e+1] + tc[2*e+1] + tw[2*e+1], 0.f);
        pk.q[e] = pk2(p0, p1);
    }
    return pk.f;
}

// ---------------- t2 fused: P_j in regs; G2 = P@W2 + b2 (LDS); T2 = Ac@G2
__global__ __launch_bounds__(256) void t2_fused(const float* __restrict__ U1,
                                                const float* __restrict__ V1,
                                                const bfu* __restrict__ acb,
                                                const float* __restrict__ wl1,
                                                const float* __restrict__ bv1,
                                                const bfu* __restrict__ T1,
                                                const bfu* __restrict__ W2t,
                                                const float* __restrict__ bv2,
                                                bfu* __restrict__ T2, int b0) {
    int bl = blockIdx.x >> 7, j = blockIdx.x & 127;
    int b = b0 + bl;
    int t = threadIdx.x, lane = t & 63, wid = t >> 6;
    int l16 = lane & 15, g4 = lane >> 4;
    __shared__ bfu lds[128 * 72];   // Gt[64][136] then stage[128][72]
    const float* U1b = U1 + (size_t)b * N * H;
    const float* V1b = V1 + (size_t)b * N * H;
    const bfu* T1b = T1 + (size_t)bl * N * N * H;
    // build P fragments in registers
    bf16x8 pa[2][2];
#pragma unroll
    for (int m = 0; m < 2; ++m) {
        int w = wid * 32 + m * 16 + l16;
        float a = b2f(acb[((size_t)b * N + j) * N + w]);
#pragma unroll
        for (int ks = 0; ks < 2; ++ks)
            pa[m][ks] = build_pa(U1b, V1b, a, wl1, bv1, T1b, j, w, ks * 32 + g4 * 8);
    }
    // phase A: G2 = P @ W2 + b2
    f32x4 acc[2][4];
#pragma unroll
    for (int m = 0; m < 2; ++m)
#pragma unroll
        for (int n = 0; n < 4; ++n) acc[m][n] = (f32x4){0.f, 0.f, 0.f, 0.f};
#pragma unroll
    for (int ks = 0; ks < 2; ++ks) {
        int k0 = ks * 32 + g4 * 8;
        bf16x8 bw[4];
#pragma unroll
        for (int n = 0; n < 4; ++n)
            bw[n] = *(const bf16x8*)&W2t[(l16 + 16 * n) * 64 + k0];
#pragma unroll
        for (int m = 0; m < 2; ++m)
#pragma unroll
            for (int n = 0; n < 4; ++n)
                acc[m][n] = MFMA16(pa[m][ks], bw[n], acc[m][n], 0, 0, 0);
    }
    {
        float bb[4];
#pragma unroll
        for (int n = 0; n < 4; ++n) bb[n] = bv2[l16 + 16 * n];
#pragma unroll
        for (int m = 0; m < 2; ++m)
#pragma unroll
            for (int n = 0; n < 4; ++n)
#pragma unroll
                for (int r = 0; r < 4; ++r)
                    lds[(l16 + 16 * n) * 136 + wid * 32 + m * 16 + g4 * 4 + r] =
                        f2b(acc[m][n][r] + bb[n]);
    }
    __syncthreads();
    // phase B: T2 = Ac @ G2
#pragma unroll
    for (int m = 0; m < 2; ++m)
#pragma unroll
        for (int n = 0; n < 4; ++n) acc[m][n] = (f32x4){0.f, 0.f, 0.f, 0.f};
    const bfu* Ab = acb + (size_t)b * N * N;
#pragma unroll
    for (int ks = 0; ks < 4; ++ks) {
        int k0 = ks * 32 + g4 * 8;
        bf16x8 bfr[4];
#pragma unroll
        for (int n = 0; n < 4; ++n)
            bfr[n] = *(const bf16x8*)&lds[(l16 + 16 * n) * 136 + k0];
#pragma unroll
        for (int m = 0; m < 2; ++m) {
            int i = wid * 32 + m * 16 + l16;
            bf16x8 afr = *(const bf16x8*)&Ab[(size_t)i * N + k0];
#pragma unroll
            for (int n = 0; n < 4; ++n)
                acc[m][n] = MFMA16(afr, bfr[n], acc[m][n], 0, 0, 0);
        }
    }
    __syncthreads();
#pragma unroll
    for (int m = 0; m < 2; ++m)
#pragma unroll
        for (int n = 0; n < 4; ++n)
#pragma unroll
            for (int r = 0; r < 4; ++r)
                lds[(wid * 32 + m * 16 + g4 * 4 + r) * 72 + l16 + 16 * n] = f2b(acc[m][n][r]);
    __syncthreads();
    {
        int i = t >> 1, half = t & 1;
        const uint4* src = (const uint4*)&lds[i * 72 + half * 32];
        uint4* dst = (uint4*)(T2 + (((size_t)bl * N + j) * N + i) * H + half * 32);
        dst[0] = src[0]; dst[1] = src[1]; dst[2] = src[2]; dst[3] = src[3];
    }
}

// ---------------- combine2 fused: P_i in regs; S = P@W1 + b1 (LDS);
//                  part2[b,i,d] = sum_{j>i} relu(S + T2[i,j] + T2[j,i])
__global__ __launch_bounds__(256) void combine2_fused(const float* __restrict__ U1,
                                                      const float* __restrict__ V1,
                                                      const bfu* __restrict__ acb,
                                                      const float* __restrict__ wl1,
                                                      const float* __restrict__ bv1,
                                                      const bfu* __restrict__ T1,
                                                      const bfu* __restrict__ W1t,
                                                      const float* __restrict__ bv2,
                                                      const bfu* __restrict__ T2,
                                                      float* __restrict__ part2, int b0) {
    int bl = blockIdx.x >> 7, i = blockIdx.x & 127;
    int b = b0 + bl;
    int t = threadIdx.x, lane = t & 63, wid = t >> 6;
    int l16 = lane & 15, g4 = lane >> 4;
    __shared__ float S[128 * 68];   // 34.8 KB; reused as red[32][64]
    const float* U1b = U1 + (size_t)b * N * H;
    const float* V1b = V1 + (size_t)b * N * H;
    const bfu* T1b = T1 + (size_t)bl * N * N * H;
    bf16x8 pa[2][2];
#pragma unroll
    for (int m = 0; m < 2; ++m) {
        int w = wid * 32 + m * 16 + l16;
        float a = b2f(acb[((size_t)b * N + i) * N + w]);
#pragma unroll
        for (int ks = 0; ks < 2; ++ks)
            pa[m][ks] = build_pa(U1b, V1b, a, wl1, bv1, T1b, i, w, ks * 32 + g4 * 8);
    }
    f32x4 acc[2][4];
#pragma unroll
    for (int m = 0; m < 2; ++m)
#pragma unroll
        for (int n = 0; n < 4; ++n) acc[m][n] = (f32x4){0.f, 0.f, 0.f, 0.f};
#pragma unroll
    for (int ks = 0; ks < 2; ++ks) {
        int k0 = ks * 32 + g4 * 8;
        bf16x8 bw[4];
#pragma unroll
        for (int n = 0; n < 4; ++n)
            bw[n] = *(const bf16x8*)&W1t[(l16 + 16 * n) * 64 + k0];
#pragma unroll
        for (int m = 0; m < 2; ++m)
#pragma unroll
            for (int n = 0; n < 4; ++n)
                acc[m][n] = MFMA16(pa[m][ks], bw[n], acc[m][n], 0, 0, 0);
    }
    {
        float bb[4];
#pragma unroll
        for (int n = 0; n < 4; ++n) bb[n] = bv2[l16 + 16 * n];
#pragma unroll
        for (int m = 0; m < 2; ++m)
#pragma unroll
            for (int n = 0; n < 4; ++n)
#pragma unroll
                for (int r = 0; r < 4; ++r)
                    S[(wid * 32 + m * 16 + g4 * 4 + r) * 68 + l16 + 16 * n] =
                        acc[m][n][r] + bb[n];
    }
    __syncthreads();
    // masked relu-sum over j>i
    int dc = t & 7, jg = t >> 3, d0 = dc * 8;
    float ps[8];
#pragma unroll
    for (int e = 0; e < 8; ++e) ps[e] = 0.f;
    const bfu* T2b = T2 + (size_t)bl * N * N * H;
#pragma unroll
    for (int r = 0; r < 4; ++r) {
        int j = jg + r * 32;
        if (j > i) {
            float ti[8], tj[8];
            up8(*(const uint4*)&T2b[((size_t)i * N + j) * H + d0], ti);
            up8(*(const uint4*)&T2b[((size_t)j * N + i) * H + d0], tj);
            const float* sr = &S[j * 68 + d0];
#pragma unroll
            for (int e = 0; e < 8; ++e)
                ps[e] += fmaxf(sr[e] + ti[e] + tj[e], 0.f);
        }
    }
    __syncthreads();
    float* red = S;
#pragma unroll
    for (int e = 0; e < 8; ++e) red[jg * 64 + d0 + e] = ps[e];
    __syncthreads();
    if (t < 64) {
        float s = 0.f;
#pragma unroll 8
        for (int g = 0; g < 32; ++g) s += red[g * 64 + t];
        part2[((size_t)b * N + i) * H + t] = s;
    }
}

// ---------------- final head
__global__ __launch_bounds__(64) void final_kernel(const float* __restrict__ emb1,
                                                   const float* __restrict__ emb2,
                                                   const float* __restrict__ cw,
                                                   const float* __restrict__ cb,
                                                   float* __restrict__ out) {
    int b = blockIdx.x;
    int c = threadIdx.x;
    if (c < C) {
        float acc = cb[c];
#pragma unroll 8
        for (int k = 0; k < H; ++k) acc += emb1[(size_t)b * H + k] * cw[(size_t)k * C + c];
#pragma unroll 8
        for (int k = 0; k < H; ++k) acc += emb2[(size_t)b * H + k] * cw[(size_t)(H + k) * C + c];
        out[(size_t)b * C + c] = acc;
    }
}

extern "C" void kernel_launch(void* const* d_in, const int* in_sizes, int n_in,
                              void* d_out, int out_size, void* d_ws, size_t ws_size,
                              hipStream_t stream) {
    const float* x    = (const float*)d_in[0];
    const float* adj  = (const float*)d_in[1];
    const float* w11  = (const float*)d_in[2];
    const float* b11  = (const float*)d_in[3];
    const float* w12  = (const float*)d_in[4];
    const float* b12  = (const float*)d_in[5];
    const float* w21  = (const float*)d_in[6];
    const float* b21  = (const float*)d_in[7];
    const float* w22  = (const float*)d_in[8];
    const float* b22  = (const float*)d_in[9];
    const float* p1w1 = (const float*)d_in[10];
    const float* p1b1 = (const float*)d_in[11];
    const float* p1w2 = (const float*)d_in[12];
    const float* p1b2 = (const float*)d_in[13];
    const float* p2w1 = (const float*)d_in[14];
    const float* p2b1 = (const float*)d_in[15];
    const float* p2w2 = (const float*)d_in[16];
    const float* p2b2 = (const float*)d_in[17];
    const float* cw   = (const float*)d_in[18];
    const float* cb   = (const float*)d_in[19];
    float* out = (float*)d_out;

    const size_t NBH = (size_t)B * N * H;            // 262144
    const size_t BIG = (size_t)N * N * H;            // 1,048,576

    float* ws = (float*)d_ws;
    float* y1    = ws;                               // NBH
    float* y2    = y1 + NBH;
    float* h1    = y2 + NBH;
    float* h2    = h1 + NBH;
    float* U1    = h2 + NBH;
    float* V1    = U1 + NBH;
    float* U2    = V1 + NBH;
    float* V2    = U2 + NBH;
    float* part2 = V2 + NBH;
    float* emb1  = part2 + NBH;                      // B*H
    float* emb2  = emb1 + (size_t)B * H;             // B*H
    size_t smallBytes = (9 * NBH + 2 * (size_t)B * H) * sizeof(float);   // ~9.45 MB

    bfu* acb = (bfu*)((char*)d_ws + smallBytes);     // B*N*N bf16 = 1 MB
    size_t acBytes = (size_t)B * N * N * sizeof(bfu);
    bfu* W1t = acb + (size_t)B * N * N;              // 64*64
    bfu* W2t = W1t + 64 * 64;
    size_t wtBytes = 2 * 64 * 64 * sizeof(bfu);

    // pick largest batch-chunk whose two bf16 big buffers (T1,T2) fit
    int CB = B;
    while (CB > 1 && smallBytes + acBytes + wtBytes + 2ull * CB * BIG * sizeof(bfu) > ws_size)
        CB >>= 1;
    bfu* T1 = (bfu*)((char*)d_ws + smallBytes + acBytes + wtBytes);      // CB*BIG
    bfu* T2 = T1 + (size_t)CB * BIG;                                     // CB*BIG

    // prep
    prep_ac<<<dim3(B * N * N / 1024), 256, 0, stream>>>(adj, acb);
    prep_wt<<<dim3(2), 256, 0, stream>>>(p2w1, p2w2, W1t, W2t);

    dim3 quadGrid(B * N / 4);
    // GNN layer 1
    {
        P4 p{{w11, w12}, {b11, b12}, {y1, y2}};
        lin_multi<DD, 2, true><<<quadGrid, 256, 0, stream>>>(x, p);
    }
    agg_relu4<<<quadGrid, 256, 0, stream>>>(y1, y2, adj, h1);
    // GNN layer 2
    {
        P4 p{{w21, w22}, {b21, b22}, {y1, y2}};
        lin_multi<H, 2, true><<<quadGrid, 256, 0, stream>>>(h1, p);
    }
    agg_relu4<<<quadGrid, 256, 0, stream>>>(y1, y2, adj, h2);
    // emb1
    rowsum_kernel<<<B, 64, 0, stream>>>(h2, emb1);
    // U/V projections of h2
    {
        P4 p{{p1w1, p1w1 + 64 * H, p1w2, p1w2 + 64 * H},
             {nullptr, nullptr, nullptr, nullptr},
             {U1, V1, U2, V2}};
        lin_multi<H, 4, false><<<quadGrid, 256, 0, stream>>>(h2, p);
    }

    // pair stages, chunked over batches
    for (int b0 = 0; b0 < B; b0 += CB) {
        dim3 cg(CB * N);
        t1_mfma<<<cg, 256, 0, stream>>>(U2, V2, acb, p1w2 + 128 * H, p1b2, T1, b0);
        t2_fused<<<cg, 256, 0, stream>>>(U1, V1, acb, p1w1 + 128 * H, p1b1,
                                         T1, W2t, p2b2, T2, b0);
        combine2_fused<<<cg, 256, 0, stream>>>(U1, V1, acb, p1w1 + 128 * H, p1b1,
                                               T1, W1t, p2b1, T2, part2, b0);
    }

    rowsum_kernel<<<B, 64, 0, stream>>>(part2, emb2);
    final_kernel<<<B, 64, 0, stream>>>(emb1, emb2, cw, cb, out);
}

// Round 5
// 244.155 us; speedup vs baseline: 3.3811x; 1.0391x over previous
//
#include <hip/hip_runtime.h>

#define B 32
#define N 128
#define DD 32
#define H 64
#define C 10

typedef unsigned short bfu;   // raw bf16 storage
typedef __attribute__((ext_vector_type(8))) short bf16x8;  // 8 bf16 (4 VGPRs)
typedef __attribute__((ext_vector_type(4))) float f32x4;   // MFMA accumulator

#define MFMA16 __builtin_amdgcn_mfma_f32_16x16x32_bf16

__device__ __forceinline__ float b2f(bfu v) {
    union { unsigned u; float f; } x; x.u = ((unsigned)v) << 16; return x.f;
}
__device__ __forceinline__ bfu f2b(float f) {
    union { float f; unsigned u; } x; x.f = f;
    unsigned r = x.u + 0x7fffu + ((x.u >> 16) & 1u);   // RNE
    return (bfu)(r >> 16);
}
__device__ __forceinline__ float lo2f(unsigned u) {
    union { unsigned x; float f; } c; c.x = u << 16; return c.f;
}
__device__ __forceinline__ float hi2f(unsigned u) {
    union { unsigned x; float f; } c; c.x = u & 0xffff0000u; return c.f;
}
__device__ __forceinline__ void up8(uint4 u, float* f) {
    f[0] = lo2f(u.x); f[1] = hi2f(u.x); f[2] = lo2f(u.y); f[3] = hi2f(u.y);
    f[4] = lo2f(u.z); f[5] = hi2f(u.z); f[6] = lo2f(u.w); f[7] = hi2f(u.w);
}
__device__ __forceinline__ unsigned pk2(float a, float b) {
    return (unsigned)f2b(a) | ((unsigned)f2b(b) << 16);
}

// ---------------- prep: ac_bf16[b][i][w] = bf16(adj * (1-I))
__global__ __launch_bounds__(256) void prep_ac(const float* __restrict__ adj,
                                               bfu* __restrict__ acb) {
    int idx = blockIdx.x * 256 + threadIdx.x;          // one float4 (4 elems)
    float4 v = ((const float4*)adj)[idx];
    int e0 = idx * 4;
    int w = e0 & 127;
    int i = (e0 >> 7) & 127;
    ushort4 o;
    o.x = f2b((i == w    ) ? 0.f : v.x);
    o.y = f2b((i == w + 1) ? 0.f : v.y);
    o.z = f2b((i == w + 2) ? 0.f : v.z);
    o.w = f2b((i == w + 3) ? 0.f : v.w);
    ((ushort4*)acb)[idx] = o;
}

// ---------------- prep: transposed bf16 weights Wt[d][k] = W[k][d] (64x64)
__global__ __launch_bounds__(256) void prep_wt(const float* __restrict__ W1,
                                               const float* __restrict__ W2,
                                               bfu* __restrict__ W1t,
                                               bfu* __restrict__ W2t) {
    const float* Wi = blockIdx.x ? W2 : W1;
    bfu* Wo = blockIdx.x ? W2t : W1t;
    int t = threadIdx.x; int d = t & 63, k0 = (t >> 6) * 16;
#pragma unroll
    for (int kk = 0; kk < 16; ++kk)
        Wo[d * 64 + k0 + kk] = f2b(Wi[(k0 + kk) * 64 + d]);
}

// ---------------- batched small linears: 4 rows/block, up to 4 outputs
struct P4 { const float* W[4]; const float* bia[4]; float* o[4]; };

template<int K, int NO, bool BIAS>
__global__ __launch_bounds__(256) void lin_multi(const float* __restrict__ in, P4 p) {
    int row0 = blockIdx.x * 4;
    int t = threadIdx.x; int g = t >> 6, c = t & 63;
    __shared__ float xs[4][K];
    if (t < 4 * K) xs[t / K][t % K] = in[(size_t)row0 * K + t];
    __syncthreads();
    int row = row0 + g;
#pragma unroll
    for (int o = 0; o < NO; ++o) {
        const float* W = p.W[o];
        float acc = BIAS ? p.bia[o][c] : 0.f;
#pragma unroll 8
        for (int k = 0; k < K; ++k) acc += xs[g][k] * W[k * H + c];
        p.o[o][(size_t)row * H + c] = acc;
    }
}

// ---------------- h = relu(y1 + adj @ y2), 4 rows per block
__global__ __launch_bounds__(256) void agg_relu4(const float* __restrict__ y1,
                                                 const float* __restrict__ y2,
                                                 const float* __restrict__ adj,
                                                 float* __restrict__ hout) {
    int b = blockIdx.x >> 5, i0 = (blockIdx.x & 31) * 4;
    int t = threadIdx.x; int g = t >> 6, d = t & 63;
    __shared__ float arow[4][N];
    ((float*)arow)[t]       = adj[((size_t)b * N + i0) * N + t];
    ((float*)arow)[t + 256] = adj[((size_t)b * N + i0) * N + t + 256];
    __syncthreads();
    const float* y2b = y2 + (size_t)b * N * H;
    int i = i0 + g;
    float acc = y1[((size_t)b * N + i) * H + d];
#pragma unroll 8
    for (int j = 0; j < N; ++j) acc += arow[g][j] * y2b[(size_t)j * H + d];
    hout[((size_t)b * N + i) * H + d] = fmaxf(acc, 0.f);
}

// ---------------- sum over middle axis: out[b][d] = sum_n in[b][n][d]
__global__ __launch_bounds__(64) void rowsum_kernel(const float* __restrict__ in,
                                                    float* __restrict__ out) {
    int b = blockIdx.x;
    int d = threadIdx.x;
    float acc = 0.f;
#pragma unroll 8
    for (int n = 0; n < N; ++n) acc += in[((size_t)b * N + n) * H + d];
    out[(size_t)b * H + d] = acc;
}

// ---------------- t1: T1[bl,j,i,d] = sum_w ac[b,i,w]*G[j,w,d]  via MFMA
// G[j,w,d] = U2[min(j,w),d] + V2[max(j,w),d] + ac[j,w]*wl[d] + bv[d]
__global__ __launch_bounds__(256) void t1_mfma(const float* __restrict__ U2,
                                               const float* __restrict__ V2,
                                               const bfu* __restrict__ acb,
                                               const float* __restrict__ wl,
                                               const float* __restrict__ bv,
                                               bfu* __restrict__ T, int b0) {
    int bl = blockIdx.x >> 7, j = blockIdx.x & 127;
    int b = b0 + bl;
    int t = threadIdx.x, lane = t & 63, wid = t >> 6;
    int l16 = lane & 15, g4 = lane >> 4;
    __shared__ bfu lds[128 * 72];   // Gt[64][136] (build+GEMM) then stage[128][72]
    {
        // coalesced G-build: lane -> d, wave-uniform w; j-row cached in regs
        int d = lane;
        const float* U2b = U2 + (size_t)b * N * H;
        const float* V2b = V2 + (size_t)b * N * H;
        const bfu* arow = acb + ((size_t)b * N + j) * N;
        float Uj = U2b[j * H + d], Vj = V2b[j * H + d];
        float wld = wl[d], bvd = bv[d];
#pragma unroll
        for (int p = 0; p < 4; ++p) {
            int w0 = p * 32 + wid * 8;
            unsigned q[4];
#pragma unroll
            for (int rr = 0; rr < 4; ++rr) {
                float g01[2];
#pragma unroll
                for (int hh = 0; hh < 2; ++hh) {
                    int w = w0 + rr * 2 + hh;
                    float a = b2f(arow[w]);
                    float rvar = (w < j) ? U2b[w * H + d] : V2b[w * H + d];
                    float base = (w < j) ? Vj : Uj;
                    g01[hh] = rvar + base + a * wld + bvd;
                }
                q[rr] = pk2(g01[0], g01[1]);
            }
            *(uint4*)&lds[d * 136 + w0] = make_uint4(q[0], q[1], q[2], q[3]);
        }
    }
    __syncthreads();
    f32x4 acc[2][4];
#pragma unroll
    for (int m = 0; m < 2; ++m)
#pragma unroll
        for (int n = 0; n < 4; ++n) acc[m][n] = (f32x4){0.f, 0.f, 0.f, 0.f};
    const bfu* Ab = acb + (size_t)b * N * N;
#pragma unroll
    for (int ks = 0; ks < 4; ++ks) {
        int k0 = ks * 32 + g4 * 8;
        bf16x8 bfr[4];
#pragma unroll
        for (int n = 0; n < 4; ++n)
            bfr[n] = *(const bf16x8*)&lds[(l16 + 16 * n) * 136 + k0];
#pragma unroll
        for (int m = 0; m < 2; ++m) {
            int i = wid * 32 + m * 16 + l16;
            bf16x8 afr = *(const bf16x8*)&Ab[(size_t)i * N + k0];
#pragma unroll
            for (int n = 0; n < 4; ++n)
                acc[m][n] = MFMA16(afr, bfr[n], acc[m][n], 0, 0, 0);
        }
    }
    __syncthreads();
#pragma unroll
    for (int m = 0; m < 2; ++m)
#pragma unroll
        for (int n = 0; n < 4; ++n)
#pragma unroll
            for (int r = 0; r < 4; ++r)
                lds[(wid * 32 + m * 16 + g4 * 4 + r) * 72 + l16 + 16 * n] = f2b(acc[m][n][r]);
    __syncthreads();
    {
        int i = t >> 1, half = t & 1;
        const uint4* src = (const uint4*)&lds[i * 72 + half * 32];
        uint4* dst = (uint4*)(T + (((size_t)bl * N + j) * N + i) * H + half * 32);
        dst[0] = src[0]; dst[1] = src[1]; dst[2] = src[2]; dst[3] = src[3];
    }
}

// ---------------- coalesced P-row build into LDS: P[w][d] for block-row c
// P[w][d] = relu(U1[min(c,w),d] + V1[max(c,w),d] + ac[c,w]*wl1[d] + bv1[d]
//               + T1[c,w,d] + T1[w,c,d])       (lane = d, wave-uniform w)
__device__ __forceinline__ void build_P_lds(bfu* Pl, const float* U1b,
                                            const float* V1b, const bfu* arow,
                                            const bfu* T1b, const float* wl1,
                                            const float* bv1, int c, int lane, int wid) {
    int d = lane;
    float Uc = U1b[c * H + d], Vc = V1b[c * H + d];
    float wld = wl1[d], bvd = bv1[d];
    const bfu* Trow = T1b + (size_t)c * N * H + d;   // + w*H
    const bfu* Tcol = T1b + (size_t)c * H + d;       // + w*N*H
#pragma unroll 4
    for (int ww = 0; ww < 32; ++ww) {
        int w = wid * 32 + ww;
        float a = b2f(arow[w]);
        float rvar = (w < c) ? U1b[w * H + d] : V1b[w * H + d];
        float base = (w < c) ? Vc : Uc;
        float tc = b2f(Trow[(size_t)w * H]);
        float tw = b2f(Tcol[(size_t)w * N * H]);
        Pl[w * 72 + d] = f2b(fmaxf(rvar + base + a * wld + bvd + tc + tw, 0.f));
    }
}

// ---------------- t2 fused: P_j in LDS; G2 = P@W2 + b2 (LDS); T2 = Ac@G2
__global__ __launch_bounds__(256) void t2_fused(const float* __restrict__ U1,
                                                const float* __restrict__ V1,
                                                const bfu* __restrict__ acb,
                                                const float* __restrict__ wl1,
                                                const float* __restrict__ bv1,
                                                const bfu* __restrict__ T1,
                                                const bfu* __restrict__ W2t,
                                                const float* __restrict__ bv2,
                                                bfu* __restrict__ T2, int b0) {
    int bl = blockIdx.x >> 7, j = blockIdx.x & 127;
    int b = b0 + bl;
    int t = threadIdx.x, lane = t & 63, wid = t >> 6;
    int l16 = lane & 15, g4 = lane >> 4;
    __shared__ bfu P[128 * 72];    // P rows (A-operand); reused as out-stage
    __shared__ bfu Gt[64 * 136];   // G2 transposed (B-operand)
    build_P_lds(P, U1 + (size_t)b * N * H, V1 + (size_t)b * N * H,
                acb + ((size_t)b * N + j) * N, T1 + (size_t)bl * N * N * H,
                wl1, bv1, j, lane, wid);
    __syncthreads();
    // phase A: G2 = P @ W2 + b2  -> Gt[d][w]
    f32x4 acc[2][4];
#pragma unroll
    for (int m = 0; m < 2; ++m)
#pragma unroll
        for (int n = 0; n < 4; ++n) acc[m][n] = (f32x4){0.f, 0.f, 0.f, 0.f};
#pragma unroll
    for (int ks = 0; ks < 2; ++ks) {
        int k0 = ks * 32 + g4 * 8;
        bf16x8 bw[4];
#pragma unroll
        for (int n = 0; n < 4; ++n)
            bw[n] = *(const bf16x8*)&W2t[(l16 + 16 * n) * 64 + k0];
#pragma unroll
        for (int m = 0; m < 2; ++m) {
            bf16x8 afr = *(const bf16x8*)&P[(wid * 32 + m * 16 + l16) * 72 + k0];
#pragma unroll
            for (int n = 0; n < 4; ++n)
                acc[m][n] = MFMA16(afr, bw[n], acc[m][n], 0, 0, 0);
        }
    }
    {
        float bb[4];
#pragma unroll
        for (int n = 0; n < 4; ++n) bb[n] = bv2[l16 + 16 * n];
#pragma unroll
        for (int m = 0; m < 2; ++m)
#pragma unroll
            for (int n = 0; n < 4; ++n) {
                uint2 q;
                q.x = pk2(acc[m][n][0] + bb[n], acc[m][n][1] + bb[n]);
                q.y = pk2(acc[m][n][2] + bb[n], acc[m][n][3] + bb[n]);
                *(uint2*)&Gt[(l16 + 16 * n) * 136 + wid * 32 + m * 16 + g4 * 4] = q;
            }
    }
    __syncthreads();
    // phase B: T2 = Ac @ G2
#pragma unroll
    for (int m = 0; m < 2; ++m)
#pragma unroll
        for (int n = 0; n < 4; ++n) acc[m][n] = (f32x4){0.f, 0.f, 0.f, 0.f};
    const bfu* Ab = acb + (size_t)b * N * N;
#pragma unroll
    for (int ks = 0; ks < 4; ++ks) {
        int k0 = ks * 32 + g4 * 8;
        bf16x8 bfr[4];
#pragma unroll
        for (int n = 0; n < 4; ++n)
            bfr[n] = *(const bf16x8*)&Gt[(l16 + 16 * n) * 136 + k0];
#pragma unroll
        for (int m = 0; m < 2; ++m) {
            int i = wid * 32 + m * 16 + l16;
            bf16x8 afr = *(const bf16x8*)&Ab[(size_t)i * N + k0];
#pragma unroll
            for (int n = 0; n < 4; ++n)
                acc[m][n] = MFMA16(afr, bfr[n], acc[m][n], 0, 0, 0);
        }
    }
    // out-stage into P region (each wave touches only its own 32-row band)
#pragma unroll
    for (int m = 0; m < 2; ++m)
#pragma unroll
        for (int n = 0; n < 4; ++n)
#pragma unroll
            for (int r = 0; r < 4; ++r)
                P[(wid * 32 + m * 16 + g4 * 4 + r) * 72 + l16 + 16 * n] = f2b(acc[m][n][r]);
    __syncthreads();
    {
        int i = t >> 1, half = t & 1;
        const uint4* src = (const uint4*)&P[i * 72 + half * 32];
        uint4* dst = (uint4*)(T2 + (((size_t)bl * N + j) * N + i) * H + half * 32);
        dst[0] = src[0]; dst[1] = src[1]; dst[2] = src[2]; dst[3] = src[3];
    }
}

// ---------------- combine2 fused: P_i in LDS; S = P@W1 + b1 (bf16, reuses P);
//                  part2[b,i,d] = sum_{j>i} relu(S + T2[i,j] + T2[j,i])
__global__ __launch_bounds__(256) void combine2_fused(const float* __restrict__ U1,
                                                      const float* __restrict__ V1,
                                                      const bfu* __restrict__ acb,
                                                      const float* __restrict__ wl1,
                                                      const float* __restrict__ bv1,
                                                      const bfu* __restrict__ T1,
                                                      const bfu* __restrict__ W1t,
                                                      const float* __restrict__ bv2,
                                                      const bfu* __restrict__ T2,
                                                      float* __restrict__ part2, int b0) {
    int bl = blockIdx.x >> 7, i = blockIdx.x & 127;
    int b = b0 + bl;
    int t = threadIdx.x, lane = t & 63, wid = t >> 6;
    int l16 = lane & 15, g4 = lane >> 4;
    __shared__ bfu P[128 * 72];      // P rows; reused to hold S (bf16)
    __shared__ float red[32][64];    // 8 KB partial sums
    build_P_lds(P, U1 + (size_t)b * N * H, V1 + (size_t)b * N * H,
                acb + ((size_t)b * N + i) * N, T1 + (size_t)bl * N * N * H,
                wl1, bv1, i, lane, wid);
    __syncthreads();
    // phase A: S = P @ W1 + b1
    f32x4 acc[2][4];
#pragma unroll
    for (int m = 0; m < 2; ++m)
#pragma unroll
        for (int n = 0; n < 4; ++n) acc[m][n] = (f32x4){0.f, 0.f, 0.f, 0.f};
#pragma unroll
    for (int ks = 0; ks < 2; ++ks) {
        int k0 = ks * 32 + g4 * 8;
        bf16x8 bw[4];
#pragma unroll
        for (int n = 0; n < 4; ++n)
            bw[n] = *(const bf16x8*)&W1t[(l16 + 16 * n) * 64 + k0];
#pragma unroll
        for (int m = 0; m < 2; ++m) {
            bf16x8 afr = *(const bf16x8*)&P[(wid * 32 + m * 16 + l16) * 72 + k0];
#pragma unroll
            for (int n = 0; n < 4; ++n)
                acc[m][n] = MFMA16(afr, bw[n], acc[m][n], 0, 0, 0);
        }
    }
    // store S (bf16) into P region — own 32-row band, no barrier needed before
    {
        float bb[4];
#pragma unroll
        for (int n = 0; n < 4; ++n) bb[n] = bv2[l16 + 16 * n];
#pragma unroll
        for (int m = 0; m < 2; ++m)
#pragma unroll
            for (int n = 0; n < 4; ++n)
#pragma unroll
                for (int r = 0; r < 4; ++r)
                    P[(wid * 32 + m * 16 + g4 * 4 + r) * 72 + l16 + 16 * n] =
                        f2b(acc[m][n][r] + bb[n]);
    }
    __syncthreads();
    // masked relu-sum over j>i
    int dc = t & 7, jg = t >> 3, d0 = dc * 8;
    float ps[8];
#pragma unroll
    for (int e = 0; e < 8; ++e) ps[e] = 0.f;
    const bfu* T2b = T2 + (size_t)bl * N * N * H;
#pragma unroll
    for (int r = 0; r < 4; ++r) {
        int j = jg + r * 32;
        if (j > i) {
            float ti[8], tj[8], sv[8];
            up8(*(const uint4*)&T2b[((size_t)i * N + j) * H + d0], ti);
            up8(*(const uint4*)&T2b[((size_t)j * N + i) * H + d0], tj);
            up8(*(const uint4*)&P[j * 72 + d0], sv);
#pragma unroll
            for (int e = 0; e < 8; ++e)
                ps[e] += fmaxf(sv[e] + ti[e] + tj[e], 0.f);
        }
    }
#pragma unroll
    for (int e = 0; e < 8; ++e) red[jg][d0 + e] = ps[e];
    __syncthreads();
    if (t < 64) {
        float s = 0.f;
#pragma unroll 8
        for (int g = 0; g < 32; ++g) s += red[g][t];
        part2[((size_t)b * N + i) * H + t] = s;
    }
}

// ---------------- final head
__global__ __launch_bounds__(64) void final_kernel(const float* __restrict__ emb1,
                                                   const float* __restrict__ emb2,
                                                   const float* __restrict__ cw,
                                                   const float* __restrict__ cb,
                                                   float* __restrict__ out) {
    int b = blockIdx.x;
    int c = threadIdx.x;
    if (c < C) {
        float acc = cb[c];
#pragma unroll 8
        for (int k = 0; k < H; ++k) acc += emb1[(size_t)b * H + k] * cw[(size_t)k * C + c];
#pragma unroll 8
        for (int k = 0; k < H; ++k) acc += emb2[(size_t)b * H + k] * cw[(size_t)(H + k) * C + c];
        out[(size_t)b * C + c] = acc;
    }
}

extern "C" void kernel_launch(void* const* d_in, const int* in_sizes, int n_in,
                              void* d_out, int out_size, void* d_ws, size_t ws_size,
                              hipStream_t stream) {
    const float* x    = (const float*)d_in[0];
    const float* adj  = (const float*)d_in[1];
    const float* w11  = (const float*)d_in[2];
    const float* b11  = (const float*)d_in[3];
    const float* w12  = (const float*)d_in[4];
    const float* b12  = (const float*)d_in[5];
    const float* w21  = (const float*)d_in[6];
    const float* b21  = (const float*)d_in[7];
    const float* w22  = (const float*)d_in[8];
    const float* b22  = (const float*)d_in[9];
    const float* p1w1 = (const float*)d_in[10];
    const float* p1b1 = (const float*)d_in[11];
    const float* p1w2 = (const float*)d_in[12];
    const float* p1b2 = (const float*)d_in[13];
    const float* p2w1 = (const float*)d_in[14];
    const float* p2b1 = (const float*)d_in[15];
    const float* p2w2 = (const float*)d_in[16];
    const float* p2b2 = (const float*)d_in[17];
    const float* cw   = (const float*)d_in[18];
    const float* cb   = (const float*)d_in[19];
    float* out = (float*)d_out;

    const size_t NBH = (size_t)B * N * H;            // 262144
    const size_t BIG = (size_t)N * N * H;            // 1,048,576

    float* ws = (float*)d_ws;
    float* y1    = ws;                               // NBH
    float* y2    = y1 + NBH;
    float* h1    = y2 + NBH;
    float* h2    = h1 + NBH;
    float* U1    = h2 + NBH;
    float* V1    = U1 + NBH;
    float* U2    = V1 + NBH;
    float* V2    = U2 + NBH;
    float* part2 = V2 + NBH;
    float* emb1  = part2 + NBH;                      // B*H
    float* emb2  = emb1 + (size_t)B * H;             // B*H
    size_t smallBytes = (9 * NBH + 2 * (size_t)B * H) * sizeof(float);   // ~9.45 MB

    bfu* acb = (bfu*)((char*)d_ws + smallBytes);     // B*N*N bf16 = 1 MB
    size_t acBytes = (size_t)B * N * N * sizeof(bfu);
    bfu* W1t = acb + (size_t)B * N * N;              // 64*64
    bfu* W2t = W1t + 64 * 64;
    size_t wtBytes = 2 * 64 * 64 * sizeof(bfu);

    // pick largest batch-chunk whose two bf16 big buffers (T1,T2) fit
    int CB = B;
    while (CB > 1 && smallBytes + acBytes + wtBytes + 2ull * CB * BIG * sizeof(bfu) > ws_size)
        CB >>= 1;
    bfu* T1 = (bfu*)((char*)d_ws + smallBytes + acBytes + wtBytes);      // CB*BIG
    bfu* T2 = T1 + (size_t)CB * BIG;                                     // CB*BIG

    // prep
    prep_ac<<<dim3(B * N * N / 1024), 256, 0, stream>>>(adj, acb);
    prep_wt<<<dim3(2), 256, 0, stream>>>(p2w1, p2w2, W1t, W2t);

    dim3 quadGrid(B * N / 4);
    // GNN layer 1
    {
        P4 p{{w11, w12}, {b11, b12}, {y1, y2}};
        lin_multi<DD, 2, true><<<quadGrid, 256, 0, stream>>>(x, p);
    }
    agg_relu4<<<quadGrid, 256, 0, stream>>>(y1, y2, adj, h1);
    // GNN layer 2
    {
        P4 p{{w21, w22}, {b21, b22}, {y1, y2}};
        lin_multi<H, 2, true><<<quadGrid, 256, 0, stream>>>(h1, p);
    }
    agg_relu4<<<quadGrid, 256, 0, stream>>>(y1, y2, adj, h2);
    // emb1
    rowsum_kernel<<<B, 64, 0, stream>>>(h2, emb1);
    // U/V projections of h2
    {
        P4 p{{p1w1, p1w1 + 64 * H, p1w2, p1w2 + 64 * H},
             {nullptr, nullptr, nullptr, nullptr},
             {U1, V1, U2, V2}};
        lin_multi<H, 4, false><<<quadGrid, 256, 0, stream>>>(h2, p);
    }

    // pair stages, chunked over batches
    for (int b0 = 0; b0 < B; b0 += CB) {
        dim3 cg(CB * N);
        t1_mfma<<<cg, 256, 0, stream>>>(U2, V2, acb, p1w2 + 128 * H, p1b2, T1, b0);
        t2_fused<<<cg, 256, 0, stream>>>(U1, V1, acb, p1w1 + 128 * H, p1b1,
                                         T1, W2t, p2b2, T2, b0);
        combine2_fused<<<cg, 256, 0, stream>>>(U1, V1, acb, p1w1 + 128 * H, p1b1,
                                               T1, W1t, p2b1, T2, part2, b0);
    }

    rowsum_kernel<<<B, 64, 0, stream>>>(part2, emb2);
    final_kernel<<<B, 64, 0, stream>>>(emb1, emb2, cw, cb, out);
}

// Round 6
// 223.026 us; speedup vs baseline: 3.7015x; 1.0947x over previous
//
#include <hip/hip_runtime.h>

#define B 32
#define N 128
#define DD 32
#define H 64
#define C 10

typedef unsigned short bfu;   // raw bf16 storage
typedef __attribute__((ext_vector_type(8))) short bf16x8;  // 8 bf16 (4 VGPRs)
typedef __attribute__((ext_vector_type(4))) float f32x4;   // MFMA accumulator

#define MFMA16 __builtin_amdgcn_mfma_f32_16x16x32_bf16

__device__ __forceinline__ float b2f(bfu v) {
    union { unsigned u; float f; } x; x.u = ((unsigned)v) << 16; return x.f;
}
// HW round-to-nearest-even f32->bf16 via compiler-native __bf16 (v_cvt_pk_bf16_f32)
__device__ __forceinline__ bfu f2b(float f) {
    union { __bf16 b; bfu u; } c; c.b = (__bf16)f; return c.u;
}
__device__ __forceinline__ float lo2f(unsigned u) {
    union { unsigned x; float f; } c; c.x = u << 16; return c.f;
}
__device__ __forceinline__ float hi2f(unsigned u) {
    union { unsigned x; float f; } c; c.x = u & 0xffff0000u; return c.f;
}
__device__ __forceinline__ void up8(uint4 u, float* f) {
    f[0] = lo2f(u.x); f[1] = hi2f(u.x); f[2] = lo2f(u.y); f[3] = hi2f(u.y);
    f[4] = lo2f(u.z); f[5] = hi2f(u.z); f[6] = lo2f(u.w); f[7] = hi2f(u.w);
}
__device__ __forceinline__ unsigned pk2(float a, float b) {
    return (unsigned)f2b(a) | ((unsigned)f2b(b) << 16);
}

// ---------------- prep: ac_bf16[b][i][w] = bf16(adj * (1-I))
__global__ __launch_bounds__(256) void prep_ac(const float* __restrict__ adj,
                                               bfu* __restrict__ acb) {
    int idx = blockIdx.x * 256 + threadIdx.x;          // one float4 (4 elems)
    float4 v = ((const float4*)adj)[idx];
    int e0 = idx * 4;
    int w = e0 & 127;
    int i = (e0 >> 7) & 127;
    ushort4 o;
    o.x = f2b((i == w    ) ? 0.f : v.x);
    o.y = f2b((i == w + 1) ? 0.f : v.y);
    o.z = f2b((i == w + 2) ? 0.f : v.z);
    o.w = f2b((i == w + 3) ? 0.f : v.w);
    ((ushort4*)acb)[idx] = o;
}

// ---------------- prep: transposed bf16 weights Wt[d][k] = W[k][d] (64x64)
__global__ __launch_bounds__(256) void prep_wt(const float* __restrict__ W1,
                                               const float* __restrict__ W2,
                                               bfu* __restrict__ W1t,
                                               bfu* __restrict__ W2t) {
    const float* Wi = blockIdx.x ? W2 : W1;
    bfu* Wo = blockIdx.x ? W2t : W1t;
    int t = threadIdx.x; int d = t & 63, k0 = (t >> 6) * 16;
#pragma unroll
    for (int kk = 0; kk < 16; ++kk)
        Wo[d * 64 + k0 + kk] = f2b(Wi[(k0 + kk) * 64 + d]);
}

// ---------------- batched small linears: 4 rows/block, up to 4 outputs
struct P4 { const float* W[4]; const float* bia[4]; float* o[4]; };

template<int K, int NO, bool BIAS>
__global__ __launch_bounds__(256) void lin_multi(const float* __restrict__ in, P4 p) {
    int row0 = blockIdx.x * 4;
    int t = threadIdx.x; int g = t >> 6, c = t & 63;
    __shared__ float xs[4][K];
    if (t < 4 * K) xs[t / K][t % K] = in[(size_t)row0 * K + t];
    __syncthreads();
    int row = row0 + g;
#pragma unroll
    for (int o = 0; o < NO; ++o) {
        const float* W = p.W[o];
        float acc = BIAS ? p.bia[o][c] : 0.f;
#pragma unroll 8
        for (int k = 0; k < K; ++k) acc += xs[g][k] * W[k * H + c];
        p.o[o][(size_t)row * H + c] = acc;
    }
}

// ---------------- h = relu(y1 + adj @ y2), 4 rows per block
__global__ __launch_bounds__(256) void agg_relu4(const float* __restrict__ y1,
                                                 const float* __restrict__ y2,
                                                 const float* __restrict__ adj,
                                                 float* __restrict__ hout) {
    int b = blockIdx.x >> 5, i0 = (blockIdx.x & 31) * 4;
    int t = threadIdx.x; int g = t >> 6, d = t & 63;
    __shared__ float arow[4][N];
    ((float*)arow)[t]       = adj[((size_t)b * N + i0) * N + t];
    ((float*)arow)[t + 256] = adj[((size_t)b * N + i0) * N + t + 256];
    __syncthreads();
    const float* y2b = y2 + (size_t)b * N * H;
    int i = i0 + g;
    float acc = y1[((size_t)b * N + i) * H + d];
#pragma unroll 8
    for (int j = 0; j < N; ++j) acc += arow[g][j] * y2b[(size_t)j * H + d];
    hout[((size_t)b * N + i) * H + d] = fmaxf(acc, 0.f);
}

// ---------------- sum over middle axis: out[b][d] = sum_n in[b][n][d]
__global__ __launch_bounds__(64) void rowsum_kernel(const float* __restrict__ in,
                                                    float* __restrict__ out) {
    int b = blockIdx.x;
    int d = threadIdx.x;
    float acc = 0.f;
#pragma unroll 8
    for (int n = 0; n < N; ++n) acc += in[((size_t)b * N + n) * H + d];
    out[(size_t)b * H + d] = acc;
}

// ---------------- t1: T1[bl,j,i,d] = sum_w ac[b,i,w]*G[j,w,d]  via MFMA
// G[j,w,d] = U2[min(j,w),d] + V2[max(j,w),d] + ac[j,w]*wl[d] + bv[d]
// Writes BOTH T1[j,i,d] and T1t[i,j,d] so consumers read contiguous panels.
__global__ __launch_bounds__(256) void t1_mfma(const float* __restrict__ U2,
                                               const float* __restrict__ V2,
                                               const bfu* __restrict__ acb,
                                               const float* __restrict__ wl,
                                               const float* __restrict__ bv,
                                               bfu* __restrict__ T,
                                               bfu* __restrict__ Tt, int b0) {
    int bl = blockIdx.x >> 7, j = blockIdx.x & 127;
    int b = b0 + bl;
    int t = threadIdx.x, lane = t & 63, wid = t >> 6;
    int l16 = lane & 15, g4 = lane >> 4;
    __shared__ bfu lds[128 * 72];   // Gt[64][136] (build+GEMM) then stage[128][72]
    __shared__ float arl[N];
    const bfu* arow = acb + ((size_t)b * N + j) * N;
    if (t < N) arl[t] = b2f(arow[t]);
    __syncthreads();
    {
        // coalesced G-build: lane -> d, wave-uniform w; a broadcast from LDS
        int d = lane;
        const float* U2b = U2 + (size_t)b * N * H;
        const float* V2b = V2 + (size_t)b * N * H;
        float wld = wl[d], bvd = bv[d];
        float UjB = U2b[j * H + d] + bvd, VjB = V2b[j * H + d] + bvd;
#pragma unroll
        for (int p = 0; p < 4; ++p) {
            int w0 = p * 32 + wid * 8;
            unsigned q[4];
#pragma unroll
            for (int rr = 0; rr < 4; ++rr) {
                float g01[2];
#pragma unroll
                for (int hh = 0; hh < 2; ++hh) {
                    int w = w0 + rr * 2 + hh;
                    float a = arl[w];
                    float rvar = (w < j) ? U2b[w * H + d] : V2b[w * H + d];
                    float base = (w < j) ? VjB : UjB;
                    g01[hh] = rvar + base + a * wld;
                }
                q[rr] = pk2(g01[0], g01[1]);
            }
            *(uint4*)&lds[d * 136 + w0] = make_uint4(q[0], q[1], q[2], q[3]);
        }
    }
    __syncthreads();
    f32x4 acc[2][4];
#pragma unroll
    for (int m = 0; m < 2; ++m)
#pragma unroll
        for (int n = 0; n < 4; ++n) acc[m][n] = (f32x4){0.f, 0.f, 0.f, 0.f};
    const bfu* Ab = acb + (size_t)b * N * N;
#pragma unroll
    for (int ks = 0; ks < 4; ++ks) {
        int k0 = ks * 32 + g4 * 8;
        bf16x8 bfr[4];
#pragma unroll
        for (int n = 0; n < 4; ++n)
            bfr[n] = *(const bf16x8*)&lds[(l16 + 16 * n) * 136 + k0];
#pragma unroll
        for (int m = 0; m < 2; ++m) {
            int i = wid * 32 + m * 16 + l16;
            bf16x8 afr = *(const bf16x8*)&Ab[(size_t)i * N + k0];
#pragma unroll
            for (int n = 0; n < 4; ++n)
                acc[m][n] = MFMA16(afr, bfr[n], acc[m][n], 0, 0, 0);
        }
    }
    __syncthreads();
#pragma unroll
    for (int m = 0; m < 2; ++m)
#pragma unroll
        for (int n = 0; n < 4; ++n)
#pragma unroll
            for (int r = 0; r < 4; ++r)
                lds[(wid * 32 + m * 16 + g4 * 4 + r) * 72 + l16 + 16 * n] = f2b(acc[m][n][r]);
    __syncthreads();
    {
        int i = t >> 1, half = t & 1;
        const uint4* src = (const uint4*)&lds[i * 72 + half * 32];
        uint4 v0 = src[0], v1 = src[1], v2 = src[2], v3 = src[3];
        uint4* dst = (uint4*)(T + (((size_t)bl * N + j) * N + i) * H + half * 32);
        dst[0] = v0; dst[1] = v1; dst[2] = v2; dst[3] = v3;
        uint4* dt = (uint4*)(Tt + (((size_t)bl * N + i) * N + j) * H + half * 32);
        dt[0] = v0; dt[1] = v1; dt[2] = v2; dt[3] = v3;
    }
}

// ---------------- vectorized P-row build into LDS: P[w][d] for block-row c
// thread -> (w = p*32 + t>>3, d0 = (t&7)*8); all loads 16B contiguous panels
// P[w][d] = relu(U1[min(c,w),d] + V1[max(c,w),d] + ac[c,w]*wl1[d] + bv1[d]
//               + Trow[w,d] + Tcol[w,d])
__device__ __forceinline__ void build_P2(bfu* Pl, const float* U1b,
                                         const float* V1b, const bfu* arow,
                                         const bfu* Trow, const bfu* Tcol,
                                         const float* wl1, const float* bv1,
                                         int c, int t) {
    int wq = t >> 3, d0 = (t & 7) * 8;
    float wv[8], bvv[8], UcB[8], VcB[8];
    *(float4*)&wv[0]  = *(const float4*)(wl1 + d0);
    *(float4*)&wv[4]  = *(const float4*)(wl1 + d0 + 4);
    *(float4*)&bvv[0] = *(const float4*)(bv1 + d0);
    *(float4*)&bvv[4] = *(const float4*)(bv1 + d0 + 4);
    *(float4*)&UcB[0] = *(const float4*)(U1b + c * H + d0);
    *(float4*)&UcB[4] = *(const float4*)(U1b + c * H + d0 + 4);
    *(float4*)&VcB[0] = *(const float4*)(V1b + c * H + d0);
    *(float4*)&VcB[4] = *(const float4*)(V1b + c * H + d0 + 4);
#pragma unroll
    for (int e = 0; e < 8; ++e) { UcB[e] += bvv[e]; VcB[e] += bvv[e]; }
#pragma unroll
    for (int p = 0; p < 4; ++p) {
        int w = p * 32 + wq;
        float a = b2f(arow[w]);
        const float* rs = (w < c) ? U1b : V1b;
        float rv[8], tc[8], tw[8];
        *(float4*)&rv[0] = *(const float4*)(rs + w * H + d0);
        *(float4*)&rv[4] = *(const float4*)(rs + w * H + d0 + 4);
        up8(*(const uint4*)&Trow[(size_t)w * H + d0], tc);
        up8(*(const uint4*)&Tcol[(size_t)w * H + d0], tw);
        unsigned q[4];
#pragma unroll
        for (int e = 0; e < 4; ++e) {
            float b0 = (w < c) ? VcB[2 * e] : UcB[2 * e];
            float b1 = (w < c) ? VcB[2 * e + 1] : UcB[2 * e + 1];
            float p0 = fmaxf(rv[2 * e]     + b0 + a * wv[2 * e]     + tc[2 * e]     + tw[2 * e],     0.f);
            float p1 = fmaxf(rv[2 * e + 1] + b1 + a * wv[2 * e + 1] + tc[2 * e + 1] + tw[2 * e + 1], 0.f);
            q[e] = pk2(p0, p1);
        }
        *(uint4*)&Pl[w * 72 + d0] = make_uint4(q[0], q[1], q[2], q[3]);
    }
}

// ---------------- t2 fused: P_j in LDS; G2 = P@W2 + b2 (LDS); T2 = Ac@G2
__global__ __launch_bounds__(256) void t2_fused(const float* __restrict__ U1,
                                                const float* __restrict__ V1,
                                                const bfu* __restrict__ acb,
                                                const float* __restrict__ wl1,
                                                const float* __restrict__ bv1,
                                                const bfu* __restrict__ T1,
                                                const bfu* __restrict__ T1t,
                                                const bfu* __restrict__ W2t,
                                                const float* __restrict__ bv2,
                                                bfu* __restrict__ T2, int b0) {
    int bl = blockIdx.x >> 7, j = blockIdx.x & 127;
    int b = b0 + bl;
    int t = threadIdx.x, lane = t & 63, wid = t >> 6;
    int l16 = lane & 15, g4 = lane >> 4;
    __shared__ bfu P[128 * 72];    // P rows (A-operand); reused as out-stage
    __shared__ bfu Gt[64 * 136];   // G2 transposed (B-operand)
    build_P2(P, U1 + (size_t)b * N * H, V1 + (size_t)b * N * H,
             acb + ((size_t)b * N + j) * N,
             T1  + ((size_t)bl * N + j) * (size_t)(N * H),
             T1t + ((size_t)bl * N + j) * (size_t)(N * H),
             wl1, bv1, j, t);
    __syncthreads();
    // phase A: G2 = P @ W2 + b2  -> Gt[d][w]
    f32x4 acc[2][4];
#pragma unroll
    for (int m = 0; m < 2; ++m)
#pragma unroll
        for (int n = 0; n < 4; ++n) acc[m][n] = (f32x4){0.f, 0.f, 0.f, 0.f};
#pragma unroll
    for (int ks = 0; ks < 2; ++ks) {
        int k0 = ks * 32 + g4 * 8;
        bf16x8 bw[4];
#pragma unroll
        for (int n = 0; n < 4; ++n)
            bw[n] = *(const bf16x8*)&W2t[(l16 + 16 * n) * 64 + k0];
#pragma unroll
        for (int m = 0; m < 2; ++m) {
            bf16x8 afr = *(const bf16x8*)&P[(wid * 32 + m * 16 + l16) * 72 + k0];
#pragma unroll
            for (int n = 0; n < 4; ++n)
                acc[m][n] = MFMA16(afr, bw[n], acc[m][n], 0, 0, 0);
        }
    }
    {
        float bb[4];
#pragma unroll
        for (int n = 0; n < 4; ++n) bb[n] = bv2[l16 + 16 * n];
#pragma unroll
        for (int m = 0; m < 2; ++m)
#pragma unroll
            for (int n = 0; n < 4; ++n) {
                uint2 q;
                q.x = pk2(acc[m][n][0] + bb[n], acc[m][n][1] + bb[n]);
                q.y = pk2(acc[m][n][2] + bb[n], acc[m][n][3] + bb[n]);
                *(uint2*)&Gt[(l16 + 16 * n) * 136 + wid * 32 + m * 16 + g4 * 4] = q;
            }
    }
    __syncthreads();
    // phase B: T2 = Ac @ G2
#pragma unroll
    for (int m = 0; m < 2; ++m)
#pragma unroll
        for (int n = 0; n < 4; ++n) acc[m][n] = (f32x4){0.f, 0.f, 0.f, 0.f};
    const bfu* Ab = acb + (size_t)b * N * N;
#pragma unroll
    for (int ks = 0; ks < 4; ++ks) {
        int k0 = ks * 32 + g4 * 8;
        bf16x8 bfr[4];
#pragma unroll
        for (int n = 0; n < 4; ++n)
            bfr[n] = *(const bf16x8*)&Gt[(l16 + 16 * n) * 136 + k0];
#pragma unroll
        for (int m = 0; m < 2; ++m) {
            int i = wid * 32 + m * 16 + l16;
            bf16x8 afr = *(const bf16x8*)&Ab[(size_t)i * N + k0];
#pragma unroll
            for (int n = 0; n < 4; ++n)
                acc[m][n] = MFMA16(afr, bfr[n], acc[m][n], 0, 0, 0);
        }
    }
    // out-stage into P region (each wave touches only its own 32-row band)
#pragma unroll
    for (int m = 0; m < 2; ++m)
#pragma unroll
        for (int n = 0; n < 4; ++n)
#pragma unroll
            for (int r = 0; r < 4; ++r)
                P[(wid * 32 + m * 16 + g4 * 4 + r) * 72 + l16 + 16 * n] = f2b(acc[m][n][r]);
    __syncthreads();
    {
        int i = t >> 1, half = t & 1;
        const uint4* src = (const uint4*)&P[i * 72 + half * 32];
        uint4* dst = (uint4*)(T2 + (((size_t)bl * N + j) * N + i) * H + half * 32);
        dst[0] = src[0]; dst[1] = src[1]; dst[2] = src[2]; dst[3] = src[3];
    }
}

// ---------------- combine2 fused: P_i in LDS; S = P@W1 + b1 (bf16, reuses P);
//                  part2[b,i,d] = sum_{j>i} relu(S + T2[i,j] + T2[j,i])
__global__ __launch_bounds__(256) void combine2_fused(const float* __restrict__ U1,
                                                      const float* __restrict__ V1,
                                                      const bfu* __restrict__ acb,
                                                      const float* __restrict__ wl1,
                                                      const float* __restrict__ bv1,
                                                      const bfu* __restrict__ T1,
                                                      const bfu* __restrict__ T1t,
                                                      const bfu* __restrict__ W1t,
                                                      const float* __restrict__ bv2,
                                                      const bfu* __restrict__ T2,
                                                      float* __restrict__ part2, int b0) {
    int bl = blockIdx.x >> 7, i = blockIdx.x & 127;
    int b = b0 + bl;
    int t = threadIdx.x, lane = t & 63, wid = t >> 6;
    int l16 = lane & 15, g4 = lane >> 4;
    __shared__ bfu P[128 * 72];      // P rows; reused to hold S (bf16)
    __shared__ float red[32][64];    // 8 KB partial sums
    build_P2(P, U1 + (size_t)b * N * H, V1 + (size_t)b * N * H,
             acb + ((size_t)b * N + i) * N,
             T1  + ((size_t)bl * N + i) * (size_t)(N * H),
             T1t + ((size_t)bl * N + i) * (size_t)(N * H),
             wl1, bv1, i, t);
    __syncthreads();
    // phase A: S = P @ W1 + b1
    f32x4 acc[2][4];
#pragma unroll
    for (int m = 0; m < 2; ++m)
#pragma unroll
        for (int n = 0; n < 4; ++n) acc[m][n] = (f32x4){0.f, 0.f, 0.f, 0.f};
#pragma unroll
    for (int ks = 0; ks < 2; ++ks) {
        int k0 = ks * 32 + g4 * 8;
        bf16x8 bw[4];
#pragma unroll
        for (int n = 0; n < 4; ++n)
            bw[n] = *(const bf16x8*)&W1t[(l16 + 16 * n) * 64 + k0];
#pragma unroll
        for (int m = 0; m < 2; ++m) {
            bf16x8 afr = *(const bf16x8*)&P[(wid * 32 + m * 16 + l16) * 72 + k0];
#pragma unroll
            for (int n = 0; n < 4; ++n)
                acc[m][n] = MFMA16(afr, bw[n], acc[m][n], 0, 0, 0);
        }
    }
    // store S (bf16) into P region — own 32-row band, no barrier needed before
    {
        float bb[4];
#pragma unroll
        for (int n = 0; n < 4; ++n) bb[n] = bv2[l16 + 16 * n];
#pragma unroll
        for (int m = 0; m < 2; ++m)
#pragma unroll
            for (int n = 0; n < 4; ++n)
#pragma unroll
                for (int r = 0; r < 4; ++r)
                    P[(wid * 32 + m * 16 + g4 * 4 + r) * 72 + l16 + 16 * n] =
                        f2b(acc[m][n][r] + bb[n]);
    }
    __syncthreads();
    // masked relu-sum over j>i
    int dc = t & 7, jg = t >> 3, d0 = dc * 8;
    float ps[8];
#pragma unroll
    for (int e = 0; e < 8; ++e) ps[e] = 0.f;
    const bfu* T2b = T2 + (size_t)bl * N * N * H;
#pragma unroll
    for (int r = 0; r < 4; ++r) {
        int j = jg + r * 32;
        if (j > i) {
            float ti[8], tj[8], sv[8];
            up8(*(const uint4*)&T2b[((size_t)i * N + j) * H + d0], ti);
            up8(*(const uint4*)&T2b[((size_t)j * N + i) * H + d0], tj);
            up8(*(const uint4*)&P[j * 72 + d0], sv);
#pragma unroll
            for (int e = 0; e < 8; ++e)
                ps[e] += fmaxf(sv[e] + ti[e] + tj[e], 0.f);
        }
    }
#pragma unroll
    for (int e = 0; e < 8; ++e) red[jg][d0 + e] = ps[e];
    __syncthreads();
    if (t < 64) {
        float s = 0.f;
#pragma unroll 8
        for (int g = 0; g < 32; ++g) s += red[g][t];
        part2[((size_t)b * N + i) * H + t] = s;
    }
}

// ---------------- final head
__global__ __launch_bounds__(64) void final_kernel(const float* __restrict__ emb1,
                                                   const float* __restrict__ emb2,
                                                   const float* __restrict__ cw,
                                                   const float* __restrict__ cb,
                                                   float* __restrict__ out) {
    int b = blockIdx.x;
    int c = threadIdx.x;
    if (c < C) {
        float acc = cb[c];
#pragma unroll 8
        for (int k = 0; k < H; ++k) acc += emb1[(size_t)b * H + k] * cw[(size_t)k * C + c];
#pragma unroll 8
        for (int k = 0; k < H; ++k) acc += emb2[(size_t)b * H + k] * cw[(size_t)(H + k) * C + c];
        out[(size_t)b * C + c] = acc;
    }
}

extern "C" void kernel_launch(void* const* d_in, const int* in_sizes, int n_in,
                              void* d_out, int out_size, void* d_ws, size_t ws_size,
                              hipStream_t stream) {
    const float* x    = (const float*)d_in[0];
    const float* adj  = (const float*)d_in[1];
    const float* w11  = (const float*)d_in[2];
    const float* b11  = (const float*)d_in[3];
    const float* w12  = (const float*)d_in[4];
    const float* b12  = (const float*)d_in[5];
    const float* w21  = (const float*)d_in[6];
    const float* b21  = (const float*)d_in[7];
    const float* w22  = (const float*)d_in[8];
    const float* b22  = (const float*)d_in[9];
    const float* p1w1 = (const float*)d_in[10];
    const float* p1b1 = (const float*)d_in[11];
    const float* p1w2 = (const float*)d_in[12];
    const float* p1b2 = (const float*)d_in[13];
    const float* p2w1 = (const float*)d_in[14];
    const float* p2b1 = (const float*)d_in[15];
    const float* p2w2 = (const float*)d_in[16];
    const float* p2b2 = (const float*)d_in[17];
    const float* cw   = (const float*)d_in[18];
    const float* cb   = (const float*)d_in[19];
    float* out = (float*)d_out;

    const size_t NBH = (size_t)B * N * H;            // 262144
    const size_t BIG = (size_t)N * N * H;            // 1,048,576

    float* ws = (float*)d_ws;
    float* y1    = ws;                               // NBH
    float* y2    = y1 + NBH;
    float* h1    = y2 + NBH;
    float* h2    = h1 + NBH;
    float* U1    = h2 + NBH;
    float* V1    = U1 + NBH;
    float* U2    = V1 + NBH;
    float* V2    = U2 + NBH;
    float* part2 = V2 + NBH;
    float* emb1  = part2 + NBH;                      // B*H
    float* emb2  = emb1 + (size_t)B * H;             // B*H
    size_t smallBytes = (9 * NBH + 2 * (size_t)B * H) * sizeof(float);   // ~9.45 MB

    bfu* acb = (bfu*)((char*)d_ws + smallBytes);     // B*N*N bf16 = 1 MB
    size_t acBytes = (size_t)B * N * N * sizeof(bfu);
    bfu* W1t = acb + (size_t)B * N * N;              // 64*64
    bfu* W2t = W1t + 64 * 64;
    size_t wtBytes = 2 * 64 * 64 * sizeof(bfu);

    // pick largest batch-chunk whose three bf16 big buffers (T1,T1t,T2) fit
    int CB = B;
    while (CB > 1 && smallBytes + acBytes + wtBytes + 3ull * CB * BIG * sizeof(bfu) > ws_size)
        CB >>= 1;
    bfu* T1  = (bfu*)((char*)d_ws + smallBytes + acBytes + wtBytes);     // CB*BIG
    bfu* T1t = T1 + (size_t)CB * BIG;                                    // CB*BIG
    bfu* T2  = T1t + (size_t)CB * BIG;                                   // CB*BIG

    // prep
    prep_ac<<<dim3(B * N * N / 1024), 256, 0, stream>>>(adj, acb);
    prep_wt<<<dim3(2), 256, 0, stream>>>(p2w1, p2w2, W1t, W2t);

    dim3 quadGrid(B * N / 4);
    // GNN layer 1
    {
        P4 p{{w11, w12}, {b11, b12}, {y1, y2}};
        lin_multi<DD, 2, true><<<quadGrid, 256, 0, stream>>>(x, p);
    }
    agg_relu4<<<quadGrid, 256, 0, stream>>>(y1, y2, adj, h1);
    // GNN layer 2
    {
        P4 p{{w21, w22}, {b21, b22}, {y1, y2}};
        lin_multi<H, 2, true><<<quadGrid, 256, 0, stream>>>(h1, p);
    }
    agg_relu4<<<quadGrid, 256, 0, stream>>>(y1, y2, adj, h2);
    // emb1
    rowsum_kernel<<<B, 64, 0, stream>>>(h2, emb1);
    // U/V projections of h2
    {
        P4 p{{p1w1, p1w1 + 64 * H, p1w2, p1w2 + 64 * H},
             {nullptr, nullptr, nullptr, nullptr},
             {U1, V1, U2, V2}};
        lin_multi<H, 4, false><<<quadGrid, 256, 0, stream>>>(h2, p);
    }

    // pair stages, chunked over batches
    for (int b0 = 0; b0 < B; b0 += CB) {
        dim3 cg(CB * N);
        t1_mfma<<<cg, 256, 0, stream>>>(U2, V2, acb, p1w2 + 128 * H, p1b2, T1, T1t, b0);
        t2_fused<<<cg, 256, 0, stream>>>(U1, V1, acb, p1w1 + 128 * H, p1b1,
                                         T1, T1t, W2t, p2b2, T2, b0);
        combine2_fused<<<cg, 256, 0, stream>>>(U1, V1, acb, p1w1 + 128 * H, p1b1,
                                               T1, T1t, W1t, p2b1, T2, part2, b0);
    }

    rowsum_kernel<<<B, 64, 0, stream>>>(part2, emb2);
    final_kernel<<<B, 64, 0, stream>>>(emb1, emb2, cw, cb, out);
}